// Round 3
// baseline (18963.342 us; speedup 1.0000x reference)
//
#include <hip/hip_runtime.h>

#define DEVINL __device__ __forceinline__

// ---------------- reduction helpers (256-thread blocks = 4 waves) ----------------
DEVINL float4 wred_max4(float4 v) {
#pragma unroll
  for (int o = 32; o; o >>= 1) {
    v.x = fmaxf(v.x, __shfl_down(v.x, o));
    v.y = fmaxf(v.y, __shfl_down(v.y, o));
    v.z = fmaxf(v.z, __shfl_down(v.z, o));
    v.w = fmaxf(v.w, __shfl_down(v.w, o));
  }
  return v;
}
DEVINL float4 wred_sum4(float4 v) {
#pragma unroll
  for (int o = 32; o; o >>= 1) {
    v.x += __shfl_down(v.x, o);
    v.y += __shfl_down(v.y, o);
    v.z += __shfl_down(v.z, o);
    v.w += __shfl_down(v.w, o);
  }
  return v;
}
DEVINL float4 block_max4(float4 v, float4* sh) {
  const int lane = threadIdx.x & 63, wid = threadIdx.x >> 6;
  v = wred_max4(v);
  __syncthreads();
  if (lane == 0) sh[wid] = v;
  __syncthreads();
  float4 a = sh[0], b = sh[1], c = sh[2], d = sh[3], r;
  r.x = fmaxf(fmaxf(a.x, b.x), fmaxf(c.x, d.x));
  r.y = fmaxf(fmaxf(a.y, b.y), fmaxf(c.y, d.y));
  r.z = fmaxf(fmaxf(a.z, b.z), fmaxf(c.z, d.z));
  r.w = fmaxf(fmaxf(a.w, b.w), fmaxf(c.w, d.w));
  return r;
}
DEVINL float4 block_sum4(float4 v, float4* sh) {
  const int lane = threadIdx.x & 63, wid = threadIdx.x >> 6;
  v = wred_sum4(v);
  __syncthreads();
  if (lane == 0) sh[wid] = v;
  __syncthreads();
  float4 a = sh[0], b = sh[1], c = sh[2], d = sh[3], r;
  r.x = a.x + b.x + c.x + d.x;
  r.y = a.y + b.y + c.y + d.y;
  r.z = a.z + b.z + c.z + d.z;
  r.w = a.w + b.w + c.w + d.w;
  return r;
}
DEVINL float block_sum1(float v, float* sh) {
  const int lane = threadIdx.x & 63, wid = threadIdx.x >> 6;
#pragma unroll
  for (int o = 32; o; o >>= 1) v += __shfl_down(v, o);
  __syncthreads();
  if (lane == 0) sh[wid] = v;
  __syncthreads();
  return sh[0] + sh[1] + sh[2] + sh[3];
}

// ---- P[v,:] = V[v,:] @ W (v<nvec), P[nvec,:] = bias @ W.  W: 512x512 ----
__global__ __launch_bounds__(256) void vecmat_kernel(
    const float* __restrict__ V, const float* __restrict__ bias,
    const float* __restrict__ W, float* __restrict__ P, int nvec) {
  const int j = blockIdx.x * 256 + threadIdx.x;  // 512 columns
  float acc[3] = {0.f, 0.f, 0.f};
  float accb = 0.f;
  for (int k = 0; k < 512; ++k) {
    const float w = W[(size_t)k * 512 + j];
    for (int v = 0; v < nvec; ++v) acc[v] += V[(size_t)v * 512 + k] * w;
    accb += bias[k] * w;
  }
  for (int v = 0; v < nvec; ++v) P[(size_t)v * 512 + j] = acc[v];
  P[(size_t)nvec * 512 + j] = accb;
}

// ---- out[r,:] = cx[r]*W3[0,:] + y0*W3[1,:] + y1*W3[2,:] + bias ----
__global__ __launch_bounds__(512) void affine3_kernel(
    const float* __restrict__ cx, const float* __restrict__ cy, int sel,
    const float* __restrict__ W3, const float* __restrict__ bias,
    float* __restrict__ out) {
  const int r = blockIdx.x, j = threadIdx.x;
  const float* y = cy + (size_t)r * 8 + 2 * sel;
  out[(size_t)r * 512 + j] =
      cx[r] * W3[j] + y[0] * W3[512 + j] + y[1] * W3[1024 + j] + bias[j];
}

// ---- out[r,:] = x[r]*w + b ----
__global__ __launch_bounds__(512) void rank1_kernel(
    const float* __restrict__ x, const float* __restrict__ w,
    const float* __restrict__ b, float* __restrict__ out) {
  const int r = blockIdx.x, j = threadIdx.x;
  out[(size_t)r * 512 + j] = x[r] * w[j] + b[j];
}

// ---------------- generic GEMM: C = [A0 | A1] @ W (+bias), all f32 ----------------
// A0: M x K0, A1: M x K1 (nullptr if K1==0), W: (K0+K1) x N row-major.
__global__ __launch_bounds__(256) void gemm_kernel(
    const float* __restrict__ A0, int K0, const float* __restrict__ A1, int K1,
    const float* __restrict__ W, const float* __restrict__ bias,
    float* __restrict__ C, int M, int N) {
  constexpr int BM = 64, BN = 64, BK = 16;
  __shared__ __align__(16) float As[BK][BM + 4];
  __shared__ __align__(16) float Bs[BK][BN + 4];
  const int tid = threadIdx.x;
  const int bm = blockIdx.y * BM, bn = blockIdx.x * BN;
  const int tx = tid & 15, ty = tid >> 4;        // 16x16 threads, 4x4 micro-tile
  const int ar = tid >> 2, ac4 = (tid & 3) * 4;  // A-tile load map (64 x 16)
  const int br = tid >> 4, bc4 = (tid & 15) * 4; // B-tile load map (16 x 64)
  const int K = K0 + K1;
  float acc[4][4] = {};
  for (int k0 = 0; k0 < K; k0 += BK) {
    const float* A;
    int kk, Ak;
    if (k0 < K0) { A = A0; kk = k0;      Ak = K0; }
    else         { A = A1; kk = k0 - K0; Ak = K1; }
    const float4 a4 = *(const float4*)(A + (size_t)(bm + ar) * Ak + kk + ac4);
    const float4 b4 = *(const float4*)(W + (size_t)(k0 + br) * N + bn + bc4);
    __syncthreads();
    As[ac4 + 0][ar] = a4.x; As[ac4 + 1][ar] = a4.y;
    As[ac4 + 2][ar] = a4.z; As[ac4 + 3][ar] = a4.w;
    Bs[br][bc4 + 0] = b4.x; Bs[br][bc4 + 1] = b4.y;
    Bs[br][bc4 + 2] = b4.z; Bs[br][bc4 + 3] = b4.w;
    __syncthreads();
#pragma unroll
    for (int k = 0; k < BK; ++k) {
      const float4 av = *(const float4*)&As[k][ty * 4];
      const float4 bv = *(const float4*)&Bs[k][tx * 4];
      const float a[4] = {av.x, av.y, av.z, av.w};
      const float bb[4] = {bv.x, bv.y, bv.z, bv.w};
#pragma unroll
      for (int i = 0; i < 4; ++i)
#pragma unroll
        for (int j = 0; j < 4; ++j) acc[i][j] += a[i] * bb[j];
    }
  }
  float bv4[4] = {0.f, 0.f, 0.f, 0.f};
  if (bias) {
#pragma unroll
    for (int j = 0; j < 4; ++j) bv4[j] = bias[bn + tx * 4 + j];
  }
#pragma unroll
  for (int i = 0; i < 4; ++i) {
    const int row = bm + ty * 4 + i;
    float4 o;
    o.x = acc[i][0] + bv4[0]; o.y = acc[i][1] + bv4[1];
    o.z = acc[i][2] + bv4[2]; o.w = acc[i][3] + bv4[3];
    *(float4*)(C + (size_t)row * N + bn + tx * 4) = o;
  }
}

// ---------------- fused multi-combo attention (f32) ----------------
// One block: 4 query rows of one (b, head). Sums ncombo sdpa terms:
//   c=0:(Qa,Ka,Va) c=1:(Qb,Kb,Vb) c=2:(Qb,Ka,Va) c=3:(Qa,Kb,Vb)
template <int D>
__global__ __launch_bounds__(256) void attn_kernel(
    const float* __restrict__ Qa, const float* __restrict__ Ka, const float* __restrict__ Va,
    const float* __restrict__ Qb, const float* __restrict__ Kb, const float* __restrict__ Vb,
    int ncombo, float post_scale, float scale, int nh, float* __restrict__ R) {
  constexpr int S = 1024;
  constexpr int DPT = D / 64;  // dims per thread in phase 2 (4 or 2)
  constexpr int QT = 4;        // query rows per block
  const int tid = threadIdx.x;
  const int qb = blockIdx.x % (S / QT);
  const int bh = blockIdx.x / (S / QT);
  const int head = bh % nh;
  const int b = bh / nh;
  const int H = 512;  // nh * D == 512 in all uses
  const size_t base = (size_t)b * S * H + (size_t)head * D;

  __shared__ __align__(16) float q_sh[QT][D];
  __shared__ __align__(16) float4 sc4[S];   // per-key: scores for the 4 query rows
  __shared__ __align__(16) float4 red4[4];
  __shared__ __align__(16) float accsh[4][D];

  const int dg = tid & 63, kg = tid >> 6;
  float oacc[QT][DPT];
#pragma unroll
  for (int i = 0; i < QT; ++i)
#pragma unroll
    for (int j = 0; j < DPT; ++j) oacc[i][j] = 0.f;

  for (int c = 0; c < ncombo; ++c) {
    const float* Q = (c == 1 || c == 2) ? Qb : Qa;
    const float* K = (c == 1 || c == 3) ? Kb : Ka;
    const float* V = (c == 1 || c == 3) ? Vb : Va;
    __syncthreads();  // previous combo's readers of q_sh/sc4 are done
    for (int i = tid; i < QT * D; i += 256) {
      const int qt = i / D, dd = i % D;
      q_sh[qt][dd] = Q[base + (size_t)(qb * QT + qt) * H + dd];
    }
    __syncthreads();
    // ---- phase 1: scores, 4 keys/thread x 4 query rows ----
    float4 sacc[4];
#pragma unroll
    for (int u = 0; u < 4; ++u) sacc[u] = make_float4(0.f, 0.f, 0.f, 0.f);
    const float* K0p = K + base;
#pragma unroll 4
    for (int dd = 0; dd < D; dd += 4) {
      const float4 q0 = *(const float4*)&q_sh[0][dd];
      const float4 q1 = *(const float4*)&q_sh[1][dd];
      const float4 q2 = *(const float4*)&q_sh[2][dd];
      const float4 q3 = *(const float4*)&q_sh[3][dd];
#pragma unroll
      for (int u = 0; u < 4; ++u) {
        const float4 kv = *(const float4*)(K0p + (size_t)(u * 256 + tid) * H + dd);
        sacc[u].x += q0.x * kv.x + q0.y * kv.y + q0.z * kv.z + q0.w * kv.w;
        sacc[u].y += q1.x * kv.x + q1.y * kv.y + q1.z * kv.z + q1.w * kv.w;
        sacc[u].z += q2.x * kv.x + q2.y * kv.y + q2.z * kv.z + q2.w * kv.w;
        sacc[u].w += q3.x * kv.x + q3.y * kv.y + q3.z * kv.z + q3.w * kv.w;
      }
    }
    float4 lmax = make_float4(-3e38f, -3e38f, -3e38f, -3e38f);
#pragma unroll
    for (int u = 0; u < 4; ++u) {
      float4 s = sacc[u];
      s.x *= scale; s.y *= scale; s.z *= scale; s.w *= scale;
      sc4[u * 256 + tid] = s;
      lmax.x = fmaxf(lmax.x, s.x); lmax.y = fmaxf(lmax.y, s.y);
      lmax.z = fmaxf(lmax.z, s.z); lmax.w = fmaxf(lmax.w, s.w);
    }
    const float4 m = block_max4(lmax, red4);
    float4 lsum = make_float4(0.f, 0.f, 0.f, 0.f);
#pragma unroll
    for (int u = 0; u < 4; ++u) {
      float4 s = sc4[u * 256 + tid];
      s.x = __expf(s.x - m.x); s.y = __expf(s.y - m.y);
      s.z = __expf(s.z - m.z); s.w = __expf(s.w - m.w);
      sc4[u * 256 + tid] = s;
      lsum.x += s.x; lsum.y += s.y; lsum.z += s.z; lsum.w += s.w;
    }
    const float4 dsum = block_sum4(lsum, red4);  // its barrier publishes sc4
    float4 inv;
    inv.x = 1.f / dsum.x; inv.y = 1.f / dsum.y;
    inv.z = 1.f / dsum.z; inv.w = 1.f / dsum.w;
    // ---- phase 2: out += P V; keys split over 4 groups, dims over 64 lanes ----
    const float* V0p = V + base + dg * DPT;
#pragma unroll 4
    for (int u = 0; u < 256; ++u) {
      const int k = kg * 256 + u;
      float4 p = sc4[k];
      p.x *= inv.x; p.y *= inv.y; p.z *= inv.z; p.w *= inv.w;
      if constexpr (DPT == 4) {
        const float4 v4 = *(const float4*)(V0p + (size_t)k * H);
        oacc[0][0] += p.x * v4.x; oacc[0][1] += p.x * v4.y;
        oacc[0][2] += p.x * v4.z; oacc[0][3] += p.x * v4.w;
        oacc[1][0] += p.y * v4.x; oacc[1][1] += p.y * v4.y;
        oacc[1][2] += p.y * v4.z; oacc[1][3] += p.y * v4.w;
        oacc[2][0] += p.z * v4.x; oacc[2][1] += p.z * v4.y;
        oacc[2][2] += p.z * v4.z; oacc[2][3] += p.z * v4.w;
        oacc[3][0] += p.w * v4.x; oacc[3][1] += p.w * v4.y;
        oacc[3][2] += p.w * v4.z; oacc[3][3] += p.w * v4.w;
      } else {
        const float2 v2 = *(const float2*)(V0p + (size_t)k * H);
        oacc[0][0] += p.x * v2.x; oacc[0][1] += p.x * v2.y;
        oacc[1][0] += p.y * v2.x; oacc[1][1] += p.y * v2.y;
        oacc[2][0] += p.z * v2.x; oacc[2][1] += p.z * v2.y;
        oacc[3][0] += p.w * v2.x; oacc[3][1] += p.w * v2.y;
      }
    }
  }
  // ---- cross-key-group reduction + store ----
#pragma unroll
  for (int qt = 0; qt < QT; ++qt) {
    __syncthreads();
#pragma unroll
    for (int j = 0; j < DPT; ++j) accsh[kg][dg * DPT + j] = oacc[qt][j];
    __syncthreads();
    if (kg == 0) {
      float* Rr = R + base + (size_t)(qb * QT + qt) * H + dg * DPT;
#pragma unroll
      for (int j = 0; j < DPT; ++j) {
        const float v = accsh[0][dg * DPT + j] + accsh[1][dg * DPT + j] +
                        accsh[2][dg * DPT + j] + accsh[3][dg * DPT + j];
        Rr[j] = v * post_scale;
      }
    }
  }
}

// ---------------- out = LayerNorm(G + res) * g + b  (+ optional copy to out2) ----------
__global__ __launch_bounds__(256) void ln_kernel(
    const float* __restrict__ G, const float* __restrict__ res,
    const float* __restrict__ g, const float* __restrict__ b,
    float* __restrict__ out, float* __restrict__ out2) {
  __shared__ float sh[4];
  const int row = blockIdx.x, tid = threadIdx.x;
  const size_t off = (size_t)row * 512;
  const float x0 = G[off + tid] + res[off + tid];
  const float x1 = G[off + tid + 256] + res[off + tid + 256];
  const float mean = block_sum1(x0 + x1, sh) * (1.0f / 512.0f);
  const float d0 = x0 - mean, d1 = x1 - mean;
  const float var = block_sum1(d0 * d0 + d1 * d1, sh) * (1.0f / 512.0f);
  const float inv = rsqrtf(var + 1e-5f);
  const float y0 = d0 * inv * g[tid] + b[tid];
  const float y1 = d1 * inv * g[tid + 256] + b[tid + 256];
  out[off + tid] = y0;
  out[off + tid + 256] = y1;
  if (out2) {
    out2[off + tid] = y0;
    out2[off + tid + 256] = y1;
  }
}

extern "C" void kernel_launch(void* const* d_in, const int* in_sizes, int n_in,
                              void* d_out, int out_size, void* d_ws, size_t ws_size,
                              hipStream_t stream) {
  const float* cx   = (const float*)d_in[0];   // (4,1024,1)
  const float* cy   = (const float*)d_in[1];   // (4,1024,8)
  const float* txp  = (const float*)d_in[2];   // (4,1024,1)
  const float* in_W = (const float*)d_in[3];   // (3,512)
  const float* in_b = (const float*)d_in[4];
  const float* cx_W = (const float*)d_in[5];   // (1,512)
  const float* cx_b = (const float*)d_in[6];
  const float* tx_W = (const float*)d_in[7];   // (1,512)
  const float* tx_b = (const float*)d_in[8];
  const float* sWk  = (const float*)d_in[9];   // (2,512,512)
  const float* sWv  = (const float*)d_in[10];
  const float* sWq  = (const float*)d_in[11];
  const float* sWf  = (const float*)d_in[12];  // (2,1024,512)
  const float* sbf  = (const float*)d_in[13];
  const float* sg   = (const float*)d_in[14];
  const float* sb   = (const float*)d_in[15];
  const float* aWk  = (const float*)d_in[16];
  const float* aWv  = (const float*)d_in[17];
  const float* aWq  = (const float*)d_in[18];
  const float* aWf  = (const float*)d_in[19];
  const float* abf  = (const float*)d_in[20];
  const float* ag   = (const float*)d_in[21];
  const float* ab   = (const float*)d_in[22];

  const int H = 512;
  const size_t MB = 1024 * 1024;
  char* ws = (char*)d_ws;
  float* E  = (float*)(ws + 0 * MB);
  float* QA = (float*)(ws + 8 * MB);
  float* Rb = (float*)(ws + 16 * MB);
  float* bK = (float*)(ws + 24 * MB);
  float* bV = (float*)(ws + 32 * MB);
  float* bQ = (float*)(ws + 40 * MB);
  float* cK = (float*)(ws + 48 * MB);
  float* cV = (float*)(ws + 56 * MB);
  float* cQ = (float*)(ws + 64 * MB);
  float* G  = cK;  // alias: cK is consumed by attn before the Wf GEMM writes G
  float* Ttab = (float*)(ws + 72 * MB);
  // T_sc[i][w] (4x512 each, w: 0=K 1=V 2=Q), then T_cak[i] (2x512), T_caq0 (2x512)
  float* T_sc[2][3];
  for (int i = 0; i < 2; ++i)
    for (int w = 0; w < 3; ++w) T_sc[i][w] = Ttab + (size_t)(i * 3 + w) * 2048;
  float* T_cak[2] = {Ttab + 12288, Ttab + 12288 + 1024};
  float* T_caq0 = Ttab + 12288 + 2048;

  const dim3 ggrid(512 / 64, 4096 / 64);

  // ---- precompute projection tables (runs once per launch; tiny) ----
  for (int i = 0; i < 2; ++i) {
    vecmat_kernel<<<2, 256, 0, stream>>>(in_W, in_b, sWk + (size_t)i * H * H, T_sc[i][0], 3);
    vecmat_kernel<<<2, 256, 0, stream>>>(in_W, in_b, sWv + (size_t)i * H * H, T_sc[i][1], 3);
    vecmat_kernel<<<2, 256, 0, stream>>>(in_W, in_b, sWq + (size_t)i * H * H, T_sc[i][2], 3);
    vecmat_kernel<<<2, 256, 0, stream>>>(cx_W, cx_b, aWk + (size_t)i * H * H, T_cak[i], 1);
  }
  vecmat_kernel<<<2, 256, 0, stream>>>(tx_W, tx_b, aWq, T_caq0, 1);

  // ---- initial activations ----
  affine3_kernel<<<4096, 512, 0, stream>>>(cx, cy, 0, in_W, in_b, E);
  rank1_kernel<<<4096, 512, 0, stream>>>(txp, tx_W, tx_b, QA);

  // ---- 8 self/cross encoder layers ----
  for (int p = 0; p < 4; ++p) {
    for (int i = 0; i < 2; ++i) {
      gemm_kernel<<<ggrid, 256, 0, stream>>>(E, 512, nullptr, 0, sWk + (size_t)i * H * H,
                                             nullptr, bK, 4096, 512);
      gemm_kernel<<<ggrid, 256, 0, stream>>>(E, 512, nullptr, 0, sWv + (size_t)i * H * H,
                                             nullptr, bV, 4096, 512);
      gemm_kernel<<<ggrid, 256, 0, stream>>>(E, 512, nullptr, 0, sWq + (size_t)i * H * H,
                                             nullptr, bQ, 4096, 512);
      if (p > 0) {
        affine3_kernel<<<4096, 512, 0, stream>>>(cx, cy, p, T_sc[i][0], T_sc[i][0] + 1536, cK);
        affine3_kernel<<<4096, 512, 0, stream>>>(cx, cy, p, T_sc[i][1], T_sc[i][1] + 1536, cV);
        affine3_kernel<<<4096, 512, 0, stream>>>(cx, cy, p, T_sc[i][2], T_sc[i][2] + 1536, cQ);
        attn_kernel<256><<<2048, 256, 0, stream>>>(bQ, bK, bV, cQ, cK, cV, 4, 1.0f,
                                                   0.0625f, 2, Rb);
      } else {
        // x2 is x: all four sdpa terms identical -> 4 * sdpa(sQ,sK,sV)
        attn_kernel<256><<<2048, 256, 0, stream>>>(bQ, bK, bV, bQ, bK, bV, 1, 4.0f,
                                                   0.0625f, 2, Rb);
      }
      gemm_kernel<<<ggrid, 256, 0, stream>>>(E, 512, Rb, 512, sWf + (size_t)i * 2 * H * H,
                                             sbf + (size_t)i * H, G, 4096, 512);
      ln_kernel<<<4096, 256, 0, stream>>>(G, E, sg + (size_t)i * H, sb + (size_t)i * H, E,
                                          nullptr);
    }
  }

  // ---- 2 cross-attention decoder layers ----
  for (int i = 0; i < 2; ++i) {
    rank1_kernel<<<4096, 512, 0, stream>>>(cx, T_cak[i], T_cak[i] + 512, bK);
    gemm_kernel<<<ggrid, 256, 0, stream>>>(E, 512, nullptr, 0, aWv + (size_t)i * H * H,
                                           nullptr, bV, 4096, 512);
    if (i == 0)
      rank1_kernel<<<4096, 512, 0, stream>>>(txp, T_caq0, T_caq0 + 512, bQ);
    else
      gemm_kernel<<<ggrid, 256, 0, stream>>>(QA, 512, nullptr, 0, aWq + (size_t)H * H,
                                             nullptr, bQ, 4096, 512);
    attn_kernel<128><<<4096, 256, 0, stream>>>(bQ, bK, bV, bQ, bK, bV, 1, 1.0f,
                                               0.08838834764831845f, 4, Rb);
    gemm_kernel<<<ggrid, 256, 0, stream>>>(QA, 512, Rb, 512, aWf + (size_t)i * 2 * H * H,
                                           abf + (size_t)i * H, G, 4096, 512);
    ln_kernel<<<4096, 256, 0, stream>>>(G, QA, ag + (size_t)i * H, ab + (size_t)i * H, QA,
                                        (i == 1) ? (float*)d_out : nullptr);
  }
  (void)in_sizes; (void)n_in; (void)out_size; (void)ws_size;
}

// Round 4
// 13628.839 us; speedup vs baseline: 1.3914x; 1.3914x over previous
//
#include <hip/hip_runtime.h>

#define DEVINL __device__ __forceinline__

typedef short bf16x8 __attribute__((ext_vector_type(8)));
typedef float f32x4 __attribute__((ext_vector_type(4)));

DEVINL unsigned short f2b(float f) {  // f32 -> bf16 (round to nearest even)
  unsigned u = __float_as_uint(f);
  u = (u + 0x7FFFu + ((u >> 16) & 1u)) >> 16;
  return (unsigned short)u;
}

// ---------------- reduction helpers (256-thread blocks = 4 waves) ----------------
DEVINL float4 wred_max4(float4 v) {
#pragma unroll
  for (int o = 32; o; o >>= 1) {
    v.x = fmaxf(v.x, __shfl_down(v.x, o));
    v.y = fmaxf(v.y, __shfl_down(v.y, o));
    v.z = fmaxf(v.z, __shfl_down(v.z, o));
    v.w = fmaxf(v.w, __shfl_down(v.w, o));
  }
  return v;
}
DEVINL float4 wred_sum4(float4 v) {
#pragma unroll
  for (int o = 32; o; o >>= 1) {
    v.x += __shfl_down(v.x, o);
    v.y += __shfl_down(v.y, o);
    v.z += __shfl_down(v.z, o);
    v.w += __shfl_down(v.w, o);
  }
  return v;
}
DEVINL float4 block_max4(float4 v, float4* sh) {
  const int lane = threadIdx.x & 63, wid = threadIdx.x >> 6;
  v = wred_max4(v);
  __syncthreads();
  if (lane == 0) sh[wid] = v;
  __syncthreads();
  float4 a = sh[0], b = sh[1], c = sh[2], d = sh[3], r;
  r.x = fmaxf(fmaxf(a.x, b.x), fmaxf(c.x, d.x));
  r.y = fmaxf(fmaxf(a.y, b.y), fmaxf(c.y, d.y));
  r.z = fmaxf(fmaxf(a.z, b.z), fmaxf(c.z, d.z));
  r.w = fmaxf(fmaxf(a.w, b.w), fmaxf(c.w, d.w));
  return r;
}
DEVINL float4 block_sum4(float4 v, float4* sh) {
  const int lane = threadIdx.x & 63, wid = threadIdx.x >> 6;
  v = wred_sum4(v);
  __syncthreads();
  if (lane == 0) sh[wid] = v;
  __syncthreads();
  float4 a = sh[0], b = sh[1], c = sh[2], d = sh[3], r;
  r.x = a.x + b.x + c.x + d.x;
  r.y = a.y + b.y + c.y + d.y;
  r.z = a.z + b.z + c.z + d.z;
  r.w = a.w + b.w + c.w + d.w;
  return r;
}
DEVINL float block_sum1(float v, float* sh) {
  const int lane = threadIdx.x & 63, wid = threadIdx.x >> 6;
#pragma unroll
  for (int o = 32; o; o >>= 1) v += __shfl_down(v, o);
  __syncthreads();
  if (lane == 0) sh[wid] = v;
  __syncthreads();
  return sh[0] + sh[1] + sh[2] + sh[3];
}

// ---- P[v,:] = V[v,:] @ W (v<nvec), P[nvec,:] = bias @ W.  W: 512x512 f32 ----
__global__ __launch_bounds__(256) void vecmat_kernel(
    const float* __restrict__ V, const float* __restrict__ bias,
    const float* __restrict__ W, float* __restrict__ P, int nvec) {
  const int j = blockIdx.x * 256 + threadIdx.x;
  float acc[3] = {0.f, 0.f, 0.f};
  float accb = 0.f;
  for (int k = 0; k < 512; ++k) {
    const float w = W[(size_t)k * 512 + j];
    for (int v = 0; v < nvec; ++v) acc[v] += V[(size_t)v * 512 + k] * w;
    accb += bias[k] * w;
  }
  for (int v = 0; v < nvec; ++v) P[(size_t)v * 512 + j] = acc[v];
  P[(size_t)nvec * 512 + j] = accb;
}

// ---- weight prep: src f32 [K][N] -> dst bf16 [N][K] ----
__global__ __launch_bounds__(256) void transpose_bf_kernel(
    const float* __restrict__ src, unsigned short* __restrict__ dst, int K, int N) {
  __shared__ float tile[32][33];
  const int n0 = blockIdx.x * 32, k0 = blockIdx.y * 32;
  const int tx = threadIdx.x, ty = threadIdx.y;  // 32 x 8
#pragma unroll
  for (int r = 0; r < 4; ++r)
    tile[ty + 8 * r][tx] = src[(size_t)(k0 + ty + 8 * r) * N + n0 + tx];
  __syncthreads();
#pragma unroll
  for (int r = 0; r < 4; ++r)
    dst[(size_t)(n0 + ty + 8 * r) * K + k0 + tx] = f2b(tile[tx][ty + 8 * r]);
}

// ---- out[r,:] = cx[r]*W3[0,:] + y0*W3[1,:] + y1*W3[2,:] + bias ----
__global__ __launch_bounds__(512) void affine3_kernel(
    const float* __restrict__ cx, const float* __restrict__ cy, int sel,
    const float* __restrict__ W3, const float* __restrict__ bias,
    float* __restrict__ out, unsigned short* __restrict__ outb) {
  const int r = blockIdx.x, j = threadIdx.x;
  const float* y = cy + (size_t)r * 8 + 2 * sel;
  const float v = cx[r] * W3[j] + y[0] * W3[512 + j] + y[1] * W3[1024 + j] + bias[j];
  if (out) out[(size_t)r * 512 + j] = v;
  if (outb) outb[(size_t)r * 512 + j] = f2b(v);
}

// ---- out[r,:] = x[r]*w + b ----
__global__ __launch_bounds__(512) void rank1_kernel(
    const float* __restrict__ x, const float* __restrict__ w,
    const float* __restrict__ b, float* __restrict__ out,
    unsigned short* __restrict__ outb) {
  const int r = blockIdx.x, j = threadIdx.x;
  const float v = x[r] * w[j] + b[j];
  if (out) out[(size_t)r * 512 + j] = v;
  if (outb) outb[(size_t)r * 512 + j] = f2b(v);
}

// ---------------- MFMA GEMM: C = [A0 | A1] @ Wt^T (+bias), bf16 in, f32 out ------
// A0: M x K0 bf16 row-major, A1: M x K1 bf16 (nullptr if K1==0).
// Wt: N x (K0+K1) bf16 row-major (i.e. W transposed). C: M x N f32.
// Tile 128(M) x 64(N) x 32(K); 4 waves, each 64x32 via 4x2 mfma_f32_16x16x32_bf16.
__global__ __launch_bounds__(256) void gemm_mfma_kernel(
    const unsigned short* __restrict__ A0, int K0,
    const unsigned short* __restrict__ A1, int K1,
    const unsigned short* __restrict__ Wt, const float* __restrict__ bias,
    float* __restrict__ C, int M, int N) {
  constexpr int BM = 128, BN = 64, BK = 32, LDP = 40;  // 40 bf16 row pitch (5 quads)
  __shared__ unsigned short As[BM * LDP];
  __shared__ unsigned short Bs[BN * LDP];
  const int tid = threadIdx.x;
  const int lane = tid & 63, w = tid >> 6;
  const int bm = blockIdx.y * BM, bn = blockIdx.x * BN;
  const int wm = (w & 1) * 64, wn = (w >> 1) * 32;
  const int l15 = lane & 15, lq = lane >> 4;  // fragment row / k-quad
  const int ar = tid >> 1, ac = (tid & 1) * 16;   // A staging: row, col(16 shorts)
  const int br = tid >> 2, bc = (tid & 3) * 8;    // B staging: row, col(8 shorts)
  const int Ktot = K0 + K1;
  f32x4 acc[4][2] = {};
  for (int k0 = 0; k0 < Ktot; k0 += BK) {
    const unsigned short* A;
    int kk, Ak;
    if (k0 < K0) { A = A0; kk = k0;      Ak = K0; }
    else         { A = A1; kk = k0 - K0; Ak = K1; }
    const uint4 a0 = *(const uint4*)(A + (size_t)(bm + ar) * Ak + kk + ac);
    const uint4 a1 = *(const uint4*)(A + (size_t)(bm + ar) * Ak + kk + ac + 8);
    const uint4 b0 = *(const uint4*)(Wt + (size_t)(bn + br) * Ktot + k0 + bc);
    __syncthreads();
    *(uint4*)(As + ar * LDP + ac) = a0;
    *(uint4*)(As + ar * LDP + ac + 8) = a1;
    *(uint4*)(Bs + br * LDP + bc) = b0;
    __syncthreads();
    bf16x8 af[4], bfr[2];
#pragma unroll
    for (int mt = 0; mt < 4; ++mt)
      af[mt] = *(const bf16x8*)(As + (wm + mt * 16 + l15) * LDP + lq * 8);
#pragma unroll
    for (int nt = 0; nt < 2; ++nt)
      bfr[nt] = *(const bf16x8*)(Bs + (wn + nt * 16 + l15) * LDP + lq * 8);
#pragma unroll
    for (int mt = 0; mt < 4; ++mt)
#pragma unroll
      for (int nt = 0; nt < 2; ++nt)
        acc[mt][nt] =
            __builtin_amdgcn_mfma_f32_16x16x32_bf16(af[mt], bfr[nt], acc[mt][nt], 0, 0, 0);
  }
  // epilogue: D lane mapping row=(lane>>4)*4+r, col=lane&15  [measured m89/m91]
#pragma unroll
  for (int nt = 0; nt < 2; ++nt) {
    const int col = bn + wn + nt * 16 + l15;
    const float bv = bias ? bias[col] : 0.f;
#pragma unroll
    for (int mt = 0; mt < 4; ++mt) {
#pragma unroll
      for (int r = 0; r < 4; ++r) {
        const int row = bm + wm + mt * 16 + lq * 4 + r;
        C[(size_t)row * N + col] = acc[mt][nt][r] + bv;
      }
    }
  }
}

// ---------------- fused multi-combo attention (f32 in, bf16 out) ----------------
// One block: 4 query rows of one (b, head). Sums ncombo sdpa terms:
//   c=0:(Qa,Ka,Va) c=1:(Qb,Kb,Vb) c=2:(Qb,Ka,Va) c=3:(Qa,Kb,Vb)
// Row strides: lda for a-side operands, ldb for b-side. R: bf16, row stride 512.
template <int D>
__global__ __launch_bounds__(256) void attn_kernel(
    const float* __restrict__ Qa, const float* __restrict__ Ka, const float* __restrict__ Va,
    const float* __restrict__ Qb, const float* __restrict__ Kb, const float* __restrict__ Vb,
    int lda, int ldb, int ncombo, float post_scale, float scale, int nh,
    unsigned short* __restrict__ R) {
  constexpr int S = 1024;
  constexpr int DPT = D / 64;  // dims per thread in phase 2 (4 or 2)
  constexpr int QT = 4;        // query rows per block
  const int tid = threadIdx.x;
  const int qb = blockIdx.x % (S / QT);
  const int bh = blockIdx.x / (S / QT);
  const int head = bh % nh;
  const int b = bh / nh;
  const size_t rowb = (size_t)b * S;
  const int colo = head * D;

  __shared__ __align__(16) float q_sh[QT][D];
  __shared__ __align__(16) float4 sc4[S];
  __shared__ __align__(16) float4 red4[4];
  __shared__ __align__(16) float accsh[4][D];

  const int dg = tid & 63, kg = tid >> 6;
  float oacc[QT][DPT];
#pragma unroll
  for (int i = 0; i < QT; ++i)
#pragma unroll
    for (int j = 0; j < DPT; ++j) oacc[i][j] = 0.f;

  for (int c = 0; c < ncombo; ++c) {
    const bool bsideQ = (c == 1 || c == 2), bsideKV = (c == 1 || c == 3);
    const float* Q = bsideQ ? Qb : Qa;
    const float* K = bsideKV ? Kb : Ka;
    const float* V = bsideKV ? Vb : Va;
    const int ldq = bsideQ ? ldb : lda;
    const int ldk = bsideKV ? ldb : lda;
    const int ldv = ldk;
    __syncthreads();
    for (int i = tid; i < QT * D; i += 256) {
      const int qt = i / D, dd = i % D;
      q_sh[qt][dd] = Q[(rowb + qb * QT + qt) * ldq + colo + dd];
    }
    __syncthreads();
    // ---- phase 1: scores, 4 keys/thread x 4 query rows ----
    float4 sacc[4];
#pragma unroll
    for (int u = 0; u < 4; ++u) sacc[u] = make_float4(0.f, 0.f, 0.f, 0.f);
    const float* K0p = K + rowb * ldk + colo;
#pragma unroll 4
    for (int dd = 0; dd < D; dd += 4) {
      const float4 q0 = *(const float4*)&q_sh[0][dd];
      const float4 q1 = *(const float4*)&q_sh[1][dd];
      const float4 q2 = *(const float4*)&q_sh[2][dd];
      const float4 q3 = *(const float4*)&q_sh[3][dd];
#pragma unroll
      for (int u = 0; u < 4; ++u) {
        const float4 kv = *(const float4*)(K0p + (size_t)(u * 256 + tid) * ldk + dd);
        sacc[u].x += q0.x * kv.x + q0.y * kv.y + q0.z * kv.z + q0.w * kv.w;
        sacc[u].y += q1.x * kv.x + q1.y * kv.y + q1.z * kv.z + q1.w * kv.w;
        sacc[u].z += q2.x * kv.x + q2.y * kv.y + q2.z * kv.z + q2.w * kv.w;
        sacc[u].w += q3.x * kv.x + q3.y * kv.y + q3.z * kv.z + q3.w * kv.w;
      }
    }
    float4 lmax = make_float4(-3e38f, -3e38f, -3e38f, -3e38f);
#pragma unroll
    for (int u = 0; u < 4; ++u) {
      float4 s = sacc[u];
      s.x *= scale; s.y *= scale; s.z *= scale; s.w *= scale;
      sc4[u * 256 + tid] = s;
      lmax.x = fmaxf(lmax.x, s.x); lmax.y = fmaxf(lmax.y, s.y);
      lmax.z = fmaxf(lmax.z, s.z); lmax.w = fmaxf(lmax.w, s.w);
    }
    const float4 m = block_max4(lmax, red4);
    float4 lsum = make_float4(0.f, 0.f, 0.f, 0.f);
#pragma unroll
    for (int u = 0; u < 4; ++u) {
      float4 s = sc4[u * 256 + tid];
      s.x = __expf(s.x - m.x); s.y = __expf(s.y - m.y);
      s.z = __expf(s.z - m.z); s.w = __expf(s.w - m.w);
      sc4[u * 256 + tid] = s;
      lsum.x += s.x; lsum.y += s.y; lsum.z += s.z; lsum.w += s.w;
    }
    const float4 dsum = block_sum4(lsum, red4);
    float4 inv;
    inv.x = 1.f / dsum.x; inv.y = 1.f / dsum.y;
    inv.z = 1.f / dsum.z; inv.w = 1.f / dsum.w;
    // ---- phase 2: out += P V; keys split over 4 groups, dims over 64 lanes ----
    const float* V0p = V + rowb * ldv + colo + dg * DPT;
#pragma unroll 4
    for (int u = 0; u < 256; ++u) {
      const int k = kg * 256 + u;
      float4 p = sc4[k];
      p.x *= inv.x; p.y *= inv.y; p.z *= inv.z; p.w *= inv.w;
      if constexpr (DPT == 4) {
        const float4 v4 = *(const float4*)(V0p + (size_t)k * ldv);
        oacc[0][0] += p.x * v4.x; oacc[0][1] += p.x * v4.y;
        oacc[0][2] += p.x * v4.z; oacc[0][3] += p.x * v4.w;
        oacc[1][0] += p.y * v4.x; oacc[1][1] += p.y * v4.y;
        oacc[1][2] += p.y * v4.z; oacc[1][3] += p.y * v4.w;
        oacc[2][0] += p.z * v4.x; oacc[2][1] += p.z * v4.y;
        oacc[2][2] += p.z * v4.z; oacc[2][3] += p.z * v4.w;
        oacc[3][0] += p.w * v4.x; oacc[3][1] += p.w * v4.y;
        oacc[3][2] += p.w * v4.z; oacc[3][3] += p.w * v4.w;
      } else {
        const float2 v2 = *(const float2*)(V0p + (size_t)k * ldv);
        oacc[0][0] += p.x * v2.x; oacc[0][1] += p.x * v2.y;
        oacc[1][0] += p.y * v2.x; oacc[1][1] += p.y * v2.y;
        oacc[2][0] += p.z * v2.x; oacc[2][1] += p.z * v2.y;
        oacc[3][0] += p.w * v2.x; oacc[3][1] += p.w * v2.y;
      }
    }
  }
  // ---- cross-key-group reduction + bf16 store ----
#pragma unroll
  for (int qt = 0; qt < QT; ++qt) {
    __syncthreads();
#pragma unroll
    for (int j = 0; j < DPT; ++j) accsh[kg][dg * DPT + j] = oacc[qt][j];
    __syncthreads();
    if (kg == 0) {
      unsigned short* Rr = R + (rowb + qb * QT + qt) * 512 + colo + dg * DPT;
      float v[DPT];
#pragma unroll
      for (int j = 0; j < DPT; ++j)
        v[j] = (accsh[0][dg * DPT + j] + accsh[1][dg * DPT + j] +
                accsh[2][dg * DPT + j] + accsh[3][dg * DPT + j]) * post_scale;
      if constexpr (DPT == 4) {
        uint2 u;
        u.x = (unsigned)f2b(v[0]) | ((unsigned)f2b(v[1]) << 16);
        u.y = (unsigned)f2b(v[2]) | ((unsigned)f2b(v[3]) << 16);
        *(uint2*)Rr = u;
      } else {
        *(unsigned*)Rr = (unsigned)f2b(v[0]) | ((unsigned)f2b(v[1]) << 16);
      }
    }
  }
}

// ------------- out = LayerNorm(G + res) * g + b  (f32 out + optional bf16 out) ----
__global__ __launch_bounds__(256) void ln_kernel(
    const float* __restrict__ G, const float* __restrict__ res,
    const float* __restrict__ g, const float* __restrict__ b,
    float* __restrict__ out, unsigned short* __restrict__ outb) {
  __shared__ float sh[4];
  const int row = blockIdx.x, tid = threadIdx.x;
  const size_t off = (size_t)row * 512;
  const float x0 = G[off + tid] + res[off + tid];
  const float x1 = G[off + tid + 256] + res[off + tid + 256];
  const float mean = block_sum1(x0 + x1, sh) * (1.0f / 512.0f);
  const float d0 = x0 - mean, d1 = x1 - mean;
  const float var = block_sum1(d0 * d0 + d1 * d1, sh) * (1.0f / 512.0f);
  const float inv = rsqrtf(var + 1e-5f);
  const float y0 = d0 * inv * g[tid] + b[tid];
  const float y1 = d1 * inv * g[tid + 256] + b[tid + 256];
  out[off + tid] = y0;
  out[off + tid + 256] = y1;
  if (outb) {
    outb[off + tid] = f2b(y0);
    outb[off + tid + 256] = f2b(y1);
  }
}

extern "C" void kernel_launch(void* const* d_in, const int* in_sizes, int n_in,
                              void* d_out, int out_size, void* d_ws, size_t ws_size,
                              hipStream_t stream) {
  typedef unsigned short ushort_t;
  const float* cx   = (const float*)d_in[0];
  const float* cy   = (const float*)d_in[1];
  const float* txp  = (const float*)d_in[2];
  const float* in_W = (const float*)d_in[3];
  const float* in_b = (const float*)d_in[4];
  const float* cx_W = (const float*)d_in[5];
  const float* cx_b = (const float*)d_in[6];
  const float* tx_W = (const float*)d_in[7];
  const float* tx_b = (const float*)d_in[8];
  const float* sWk  = (const float*)d_in[9];
  const float* sWv  = (const float*)d_in[10];
  const float* sWq  = (const float*)d_in[11];
  const float* sWf  = (const float*)d_in[12];
  const float* sbf  = (const float*)d_in[13];
  const float* sg   = (const float*)d_in[14];
  const float* sb   = (const float*)d_in[15];
  const float* aWk  = (const float*)d_in[16];
  const float* aWv  = (const float*)d_in[17];
  const float* aWq  = (const float*)d_in[18];
  const float* aWf  = (const float*)d_in[19];
  const float* abf  = (const float*)d_in[20];
  const float* ag   = (const float*)d_in[21];
  const float* ab   = (const float*)d_in[22];

  const size_t MB = 1024 * 1024;
  char* ws = (char*)d_ws;
  float*    E     = (float*)(ws + 0 * MB);       // 8 MB
  ushort_t* Ebf   = (ushort_t*)(ws + 8 * MB);    // 4 MB
  float*    QA    = (float*)(ws + 12 * MB);      // 8 MB
  ushort_t* QAbf  = (ushort_t*)(ws + 20 * MB);   // 4 MB
  ushort_t* Rbbf  = (ushort_t*)(ws + 24 * MB);   // 4 MB
  float*    KVQ   = (float*)(ws + 28 * MB);      // 24 MB  [4096][1536]
  float*    cK    = (float*)(ws + 52 * MB);      // 8 MB  (also cross xK, G alias)
  float*    cV    = (float*)(ws + 60 * MB);      // 8 MB  (also cross xV)
  float*    cQ    = (float*)(ws + 68 * MB);      // 8 MB  (also cross xQ)
  float*    G     = cK;  // written only after attn consumed cK
  ushort_t* Wkvqt[2] = {(ushort_t*)(ws + 76 * MB), (ushort_t*)(ws + 78 * MB)};  // 1.5 MB ea
  ushort_t* Wft[2]   = {(ushort_t*)(ws + 80 * MB), (ushort_t*)(ws + 81 * MB)};  // 1 MB ea
  ushort_t* aWvt[2]  = {(ushort_t*)(ws + 82 * MB), (ushort_t*)(ws + 83 * MB)};  // 0.5 MB ea
  ushort_t* aWqt1    = (ushort_t*)(ws + 84 * MB);
  ushort_t* aWft[2]  = {(ushort_t*)(ws + 85 * MB), (ushort_t*)(ws + 86 * MB)};  // 1 MB ea
  float*    Ttab     = (float*)(ws + 88 * MB);

  float* T_cak[2] = {Ttab, Ttab + 1024};
  float* T_caq0 = Ttab + 2048;

  const dim3 tb(32, 8);
  const dim3 tg512(16, 16);   // transpose grids: (N/32, K/32)
  const dim3 tg1024(16, 32);

  // ---- weight prep: transpose+convert to bf16 [N][K] ----
  for (int i = 0; i < 2; ++i) {
    transpose_bf_kernel<<<tg512, tb, 0, stream>>>(sWk + (size_t)i * 262144, Wkvqt[i], 512, 512);
    transpose_bf_kernel<<<tg512, tb, 0, stream>>>(sWv + (size_t)i * 262144, Wkvqt[i] + 512 * 512, 512, 512);
    transpose_bf_kernel<<<tg512, tb, 0, stream>>>(sWq + (size_t)i * 262144, Wkvqt[i] + 1024 * 512, 512, 512);
    transpose_bf_kernel<<<tg1024, tb, 0, stream>>>(sWf + (size_t)i * 524288, Wft[i], 1024, 512);
    transpose_bf_kernel<<<tg512, tb, 0, stream>>>(aWv + (size_t)i * 262144, aWvt[i], 512, 512);
    transpose_bf_kernel<<<tg1024, tb, 0, stream>>>(aWf + (size_t)i * 524288, aWft[i], 1024, 512);
    vecmat_kernel<<<2, 256, 0, stream>>>(cx_W, cx_b, aWk + (size_t)i * 262144, T_cak[i], 1);
  }
  transpose_bf_kernel<<<tg512, tb, 0, stream>>>(aWq + 262144, aWqt1, 512, 512);
  vecmat_kernel<<<2, 256, 0, stream>>>(tx_W, tx_b, aWq, T_caq0, 1);

  // ---- initial activations ----
  affine3_kernel<<<4096, 512, 0, stream>>>(cx, cy, 0, in_W, in_b, E, Ebf);
  rank1_kernel<<<4096, 512, 0, stream>>>(txp, tx_W, tx_b, QA, QAbf);

  // ---- 8 self/cross encoder layers ----
  for (int p = 0; p < 4; ++p) {
    for (int i = 0; i < 2; ++i) {
      gemm_mfma_kernel<<<dim3(24, 32), 256, 0, stream>>>(Ebf, 512, nullptr, 0, Wkvqt[i],
                                                         nullptr, KVQ, 4096, 1536);
      if (p > 0) {
        // cross-stream K/V/Q are rank-3 affine via precomputed in_W @ W tables
        // (e1/e2/e3 never change). Tables live in sWk/v/q^T form? No: computed below.
        // We compute them fresh each layer from the f32 weights (cheap).
      }
      if (p > 0) {
        // cK/cV/cQ = concat([cx, y_p]) @ inW @ W + inb @ W; build via vecmat tables
        // computed on the fly: reuse affine3 with precomputed 4x512 tables.
        // Tables: rows 0..2 = inW rows projected, row 3 = bias.
        // (vecmat below is launched per layer; tiny.)
      }
      if (p > 0) {
        vecmat_kernel<<<2, 256, 0, stream>>>(in_W, in_b, sWk + (size_t)i * 262144, Ttab + 4096, 3);
        vecmat_kernel<<<2, 256, 0, stream>>>(in_W, in_b, sWv + (size_t)i * 262144, Ttab + 6144, 3);
        vecmat_kernel<<<2, 256, 0, stream>>>(in_W, in_b, sWq + (size_t)i * 262144, Ttab + 8192, 3);
        affine3_kernel<<<4096, 512, 0, stream>>>(cx, cy, p, Ttab + 4096, Ttab + 4096 + 1536, cK, nullptr);
        affine3_kernel<<<4096, 512, 0, stream>>>(cx, cy, p, Ttab + 6144, Ttab + 6144 + 1536, cV, nullptr);
        affine3_kernel<<<4096, 512, 0, stream>>>(cx, cy, p, Ttab + 8192, Ttab + 8192 + 1536, cQ, nullptr);
        attn_kernel<256><<<2048, 256, 0, stream>>>(KVQ + 1024, KVQ, KVQ + 512, cQ, cK, cV,
                                                   1536, 512, 4, 1.0f, 0.0625f, 2, Rbbf);
      } else {
        attn_kernel<256><<<2048, 256, 0, stream>>>(KVQ + 1024, KVQ, KVQ + 512,
                                                   KVQ + 1024, KVQ, KVQ + 512,
                                                   1536, 1536, 1, 4.0f, 0.0625f, 2, Rbbf);
      }
      gemm_mfma_kernel<<<dim3(8, 32), 256, 0, stream>>>(Ebf, 512, Rbbf, 512, Wft[i],
                                                        sbf + (size_t)i * 512, G, 4096, 512);
      ln_kernel<<<4096, 256, 0, stream>>>(G, E, sg + (size_t)i * 512, sb + (size_t)i * 512,
                                          E, Ebf);
    }
  }

  // ---- 2 cross-attention decoder layers ----
  for (int i = 0; i < 2; ++i) {
    rank1_kernel<<<4096, 512, 0, stream>>>(cx, T_cak[i], T_cak[i] + 512, cK, nullptr);
    gemm_mfma_kernel<<<dim3(8, 32), 256, 0, stream>>>(Ebf, 512, nullptr, 0, aWvt[i],
                                                      nullptr, cV, 4096, 512);
    if (i == 0)
      rank1_kernel<<<4096, 512, 0, stream>>>(txp, T_caq0, T_caq0 + 512, cQ, nullptr);
    else
      gemm_mfma_kernel<<<dim3(8, 32), 256, 0, stream>>>(QAbf, 512, nullptr, 0, aWqt1,
                                                        nullptr, cQ, 4096, 512);
    attn_kernel<128><<<4096, 256, 0, stream>>>(cQ, cK, cV, cQ, cK, cV, 512, 512, 1, 1.0f,
                                               0.08838834764831845f, 4, Rbbf);
    gemm_mfma_kernel<<<dim3(8, 32), 256, 0, stream>>>(QAbf, 512, Rbbf, 512, aWft[i],
                                                      abf + (size_t)i * 512, G, 4096, 512);
    ln_kernel<<<4096, 256, 0, stream>>>(G, QA, ag + (size_t)i * 512, ab + (size_t)i * 512,
                                        (i == 1) ? (float*)d_out : QA,
                                        (i == 1) ? nullptr : QAbf);
  }
  (void)in_sizes; (void)n_in; (void)out_size; (void)ws_size;
}

// Round 5
// 4036.435 us; speedup vs baseline: 4.6980x; 3.3765x over previous
//
#include <hip/hip_runtime.h>

#define DEVINL __device__ __forceinline__

typedef short bf16x8 __attribute__((ext_vector_type(8)));
typedef float f32x4 __attribute__((ext_vector_type(4)));

DEVINL unsigned short f2b(float f) {  // f32 -> bf16 (round to nearest even)
  unsigned u = __float_as_uint(f);
  u = (u + 0x7FFFu + ((u >> 16) & 1u)) >> 16;
  return (unsigned short)u;
}
DEVINL float4 ldbf4u(const unsigned short* p) {  // 4 consecutive bf16 (8B aligned)
  const uint2 u = *(const uint2*)p;
  return make_float4(__uint_as_float(u.x << 16), __uint_as_float(u.x & 0xFFFF0000u),
                     __uint_as_float(u.y << 16), __uint_as_float(u.y & 0xFFFF0000u));
}
DEVINL float hmax4a(const float* v) { return fmaxf(fmaxf(v[0], v[1]), fmaxf(v[2], v[3])); }
DEVINL float hsum4a(const float* v) { return (v[0] + v[1]) + (v[2] + v[3]); }

// ---------------- reduction helpers (256-thread blocks = 4 waves) ----------------
DEVINL float4 wred_max4(float4 v) {
#pragma unroll
  for (int o = 32; o; o >>= 1) {
    v.x = fmaxf(v.x, __shfl_down(v.x, o));
    v.y = fmaxf(v.y, __shfl_down(v.y, o));
    v.z = fmaxf(v.z, __shfl_down(v.z, o));
    v.w = fmaxf(v.w, __shfl_down(v.w, o));
  }
  return v;
}
DEVINL float4 wred_sum4(float4 v) {
#pragma unroll
  for (int o = 32; o; o >>= 1) {
    v.x += __shfl_down(v.x, o);
    v.y += __shfl_down(v.y, o);
    v.z += __shfl_down(v.z, o);
    v.w += __shfl_down(v.w, o);
  }
  return v;
}
DEVINL float4 block_max4(float4 v, float4* sh) {
  const int lane = threadIdx.x & 63, wid = threadIdx.x >> 6;
  v = wred_max4(v);
  __syncthreads();
  if (lane == 0) sh[wid] = v;
  __syncthreads();
  float4 a = sh[0], b = sh[1], c = sh[2], d = sh[3], r;
  r.x = fmaxf(fmaxf(a.x, b.x), fmaxf(c.x, d.x));
  r.y = fmaxf(fmaxf(a.y, b.y), fmaxf(c.y, d.y));
  r.z = fmaxf(fmaxf(a.z, b.z), fmaxf(c.z, d.z));
  r.w = fmaxf(fmaxf(a.w, b.w), fmaxf(c.w, d.w));
  return r;
}
DEVINL float4 block_sum4(float4 v, float4* sh) {
  const int lane = threadIdx.x & 63, wid = threadIdx.x >> 6;
  v = wred_sum4(v);
  __syncthreads();
  if (lane == 0) sh[wid] = v;
  __syncthreads();
  float4 a = sh[0], b = sh[1], c = sh[2], d = sh[3], r;
  r.x = a.x + b.x + c.x + d.x;
  r.y = a.y + b.y + c.y + d.y;
  r.z = a.z + b.z + c.z + d.z;
  r.w = a.w + b.w + c.w + d.w;
  return r;
}
DEVINL float block_sum1(float v, float* sh) {
  const int lane = threadIdx.x & 63, wid = threadIdx.x >> 6;
#pragma unroll
  for (int o = 32; o; o >>= 1) v += __shfl_down(v, o);
  __syncthreads();
  if (lane == 0) sh[wid] = v;
  __syncthreads();
  return sh[0] + sh[1] + sh[2] + sh[3];
}

// ---- table projection: P[v,j] = V[v,:] @ W[:,j], P[nvec,j] = bias @ W[:,j] ----
// One block per output column j; k split over 256 threads. W: 512x512 f32.
__global__ __launch_bounds__(256) void tabproj_kernel(
    const float* __restrict__ V, const float* __restrict__ bias,
    const float* __restrict__ W, float* __restrict__ P, int nvec) {
  __shared__ float4 sh4[4];
  const int j = blockIdx.x, tid = threadIdx.x;
  float acc[4] = {0.f, 0.f, 0.f, 0.f};
  for (int kk = tid; kk < 512; kk += 256) {
    const float w = W[(size_t)kk * 512 + j];
    for (int v = 0; v < nvec; ++v) acc[v] += V[(size_t)v * 512 + kk] * w;
    acc[3] += bias[kk] * w;
  }
  float4 packed = make_float4(acc[0], acc[1], acc[2], acc[3]);
  packed = block_sum4(packed, sh4);
  if (tid == 0) {
    const float vals[4] = {packed.x, packed.y, packed.z, packed.w};
    for (int v = 0; v < nvec; ++v) P[(size_t)v * 512 + j] = vals[v];
    P[(size_t)nvec * 512 + j] = vals[3];
  }
}

// ---- weight prep: src f32 [K][N] -> dst bf16 [N][K] ----
__global__ __launch_bounds__(256) void transpose_bf_kernel(
    const float* __restrict__ src, unsigned short* __restrict__ dst, int K, int N) {
  __shared__ float tile[32][33];
  const int n0 = blockIdx.x * 32, k0 = blockIdx.y * 32;
  const int tx = threadIdx.x, ty = threadIdx.y;  // 32 x 8
#pragma unroll
  for (int r = 0; r < 4; ++r)
    tile[ty + 8 * r][tx] = src[(size_t)(k0 + ty + 8 * r) * N + n0 + tx];
  __syncthreads();
#pragma unroll
  for (int r = 0; r < 4; ++r)
    dst[(size_t)(n0 + ty + 8 * r) * K + k0 + tx] = f2b(tile[tx][ty + 8 * r]);
}

// ---- K transpose: K row-major [B*1024][ld] (head cols at h*D) -> Kt bf16 [B][nh][D][1024] --
__global__ __launch_bounds__(256) void ktrans_kernel(
    const float* __restrict__ K, int ld, int nh, int D,
    unsigned short* __restrict__ Kt) {
  __shared__ float tile[32][33];
  const int s0 = blockIdx.x * 32, d0 = blockIdx.y * 32;
  const int b = blockIdx.z / nh, h = blockIdx.z % nh;
  const int tx = threadIdx.x, ty = threadIdx.y;  // 32 x 8
  const float* src = K + ((size_t)b * 1024 + s0) * ld + h * D + d0;
#pragma unroll
  for (int r = 0; r < 4; ++r)
    tile[ty + 8 * r][tx] = src[(size_t)(ty + 8 * r) * ld + tx];  // [s][d]
  __syncthreads();
  unsigned short* dst = Kt + ((size_t)(b * nh + h) * D + d0) * 1024 + s0;
#pragma unroll
  for (int r = 0; r < 4; ++r)
    dst[(size_t)(ty + 8 * r) * 1024 + tx] = f2b(tile[tx][ty + 8 * r]);  // [d][s]
}

// ---- out[r,:] = cx[r]*W3[0,:] + y0*W3[1,:] + y1*W3[2,:] + bias ----
__global__ __launch_bounds__(512) void affine3_kernel(
    const float* __restrict__ cx, const float* __restrict__ cy, int sel,
    const float* __restrict__ W3, const float* __restrict__ bias,
    float* __restrict__ out, unsigned short* __restrict__ outb) {
  const int r = blockIdx.x, j = threadIdx.x;
  const float* y = cy + (size_t)r * 8 + 2 * sel;
  const float v = cx[r] * W3[j] + y[0] * W3[512 + j] + y[1] * W3[1024 + j] + bias[j];
  if (out) out[(size_t)r * 512 + j] = v;
  if (outb) outb[(size_t)r * 512 + j] = f2b(v);
}

// ---- out[r,:] = x[r]*w + b ----
__global__ __launch_bounds__(512) void rank1_kernel(
    const float* __restrict__ x, const float* __restrict__ w,
    const float* __restrict__ b, float* __restrict__ out,
    unsigned short* __restrict__ outb) {
  const int r = blockIdx.x, j = threadIdx.x;
  const float v = x[r] * w[j] + b[j];
  if (out) out[(size_t)r * 512 + j] = v;
  if (outb) outb[(size_t)r * 512 + j] = f2b(v);
}

// ---------------- MFMA GEMM: C = [A0 | A1] @ Wt^T (+bias), bf16 in, f32 out ------
__global__ __launch_bounds__(256) void gemm_mfma_kernel(
    const unsigned short* __restrict__ A0, int K0,
    const unsigned short* __restrict__ A1, int K1,
    const unsigned short* __restrict__ Wt, const float* __restrict__ bias,
    float* __restrict__ C, int M, int N) {
  constexpr int BM = 128, BN = 64, BK = 32, LDP = 40;
  __shared__ unsigned short As[BM * LDP];
  __shared__ unsigned short Bs[BN * LDP];
  const int tid = threadIdx.x;
  const int lane = tid & 63, w = tid >> 6;
  const int bm = blockIdx.y * BM, bn = blockIdx.x * BN;
  const int wm = (w & 1) * 64, wn = (w >> 1) * 32;
  const int l15 = lane & 15, lq = lane >> 4;
  const int ar = tid >> 1, ac = (tid & 1) * 16;
  const int br = tid >> 2, bc = (tid & 3) * 8;
  const int Ktot = K0 + K1;
  f32x4 acc[4][2] = {};
  for (int k0 = 0; k0 < Ktot; k0 += BK) {
    const unsigned short* A;
    int kk, Ak;
    if (k0 < K0) { A = A0; kk = k0;      Ak = K0; }
    else         { A = A1; kk = k0 - K0; Ak = K1; }
    const uint4 a0 = *(const uint4*)(A + (size_t)(bm + ar) * Ak + kk + ac);
    const uint4 a1 = *(const uint4*)(A + (size_t)(bm + ar) * Ak + kk + ac + 8);
    const uint4 b0 = *(const uint4*)(Wt + (size_t)(bn + br) * Ktot + k0 + bc);
    __syncthreads();
    *(uint4*)(As + ar * LDP + ac) = a0;
    *(uint4*)(As + ar * LDP + ac + 8) = a1;
    *(uint4*)(Bs + br * LDP + bc) = b0;
    __syncthreads();
    bf16x8 af[4], bfr[2];
#pragma unroll
    for (int mt = 0; mt < 4; ++mt)
      af[mt] = *(const bf16x8*)(As + (wm + mt * 16 + l15) * LDP + lq * 8);
#pragma unroll
    for (int nt = 0; nt < 2; ++nt)
      bfr[nt] = *(const bf16x8*)(Bs + (wn + nt * 16 + l15) * LDP + lq * 8);
#pragma unroll
    for (int mt = 0; mt < 4; ++mt)
#pragma unroll
      for (int nt = 0; nt < 2; ++nt)
        acc[mt][nt] =
            __builtin_amdgcn_mfma_f32_16x16x32_bf16(af[mt], bfr[nt], acc[mt][nt], 0, 0, 0);
  }
#pragma unroll
  for (int nt = 0; nt < 2; ++nt) {
    const int col = bn + wn + nt * 16 + l15;
    const float bv = bias ? bias[col] : 0.f;
#pragma unroll
    for (int mt = 0; mt < 4; ++mt) {
#pragma unroll
      for (int r = 0; r < 4; ++r) {
        const int row = bm + wm + mt * 16 + lq * 4 + r;
        C[(size_t)row * N + col] = acc[mt][nt][r] + bv;
      }
    }
  }
}

// ---------------- fused attention v2: coalesced Kt, combined-PV ----------------
// Output rows r: sum over kv sides s of [softmax(Qa_r Ks^T)+softmax(Qb_r Ks^T)] Vs
// (NKV=1: only (Qa,KtA,Va); equals single sdpa). post_scale applied at store.
template <int D, int NKV>
__global__ __launch_bounds__(256) void attn2_kernel(
    const float* __restrict__ Qa, const float* __restrict__ Qb,
    const unsigned short* __restrict__ KtA, const unsigned short* __restrict__ KtB,
    const float* __restrict__ Va, const float* __restrict__ Vb,
    int ldqa, int ldqb, int ldva, int ldvb,
    float post_scale, float scale, int nh, unsigned short* __restrict__ R) {
  constexpr int S = 1024;
  constexpr int DPT = D / 64;
  constexpr int QT = 4;
  constexpr int NQR = (NKV == 2) ? 8 : 4;
  const int tid = threadIdx.x;
  const int qb = blockIdx.x % (S / QT);
  const int bh = blockIdx.x / (S / QT);
  const int head = bh % nh;
  const int b = bh / nh;
  const size_t rowb = (size_t)b * S;
  const int colo = head * D;

  __shared__ __align__(16) float q_sh[NQR][D];
  __shared__ __align__(16) float4 sc4[S];  // combined weights: per key, 4 output rows
  __shared__ __align__(16) float4 red4[4];
  __shared__ __align__(16) float accsh[4][D];

  const int dg = tid & 63, kg = tid >> 6;
  float oacc[QT][DPT] = {};

  for (int s = 0; s < NKV; ++s) {
    const unsigned short* Kt = s ? KtB : KtA;
    const float* V = s ? Vb : Va;
    const size_t ldv = s ? ldvb : ldva;
    __syncthreads();  // previous side's phase-2 readers of sc4 done
    for (int i = tid; i < NQR * D; i += 256) {
      const int qr = i / D, dd = i - qr * D;
      const float* Q = (NKV == 2 && qr >= 4) ? Qb : Qa;
      const size_t ldq = (NKV == 2 && qr >= 4) ? ldqb : ldqa;
      q_sh[qr][dd] = Q[(rowb + qb * QT + (qr & 3)) * ldq + colo + dd];
    }
    __syncthreads();
    // ---- phase 1: thread owns keys 4*tid..4*tid+3, coalesced Kt loads ----
    float sacc[NQR][4] = {};
    const unsigned short* Ktp = Kt + ((size_t)(b * nh + head) * D) * S + 4 * tid;
#pragma unroll 2
    for (int dd = 0; dd < D; dd += 4) {
      const float4 kt0 = ldbf4u(Ktp + (size_t)(dd + 0) * S);
      const float4 kt1 = ldbf4u(Ktp + (size_t)(dd + 1) * S);
      const float4 kt2 = ldbf4u(Ktp + (size_t)(dd + 2) * S);
      const float4 kt3 = ldbf4u(Ktp + (size_t)(dd + 3) * S);
#pragma unroll
      for (int r = 0; r < NQR; ++r) {
        const float4 q = *(const float4*)&q_sh[r][dd];
        sacc[r][0] += q.x * kt0.x + q.y * kt1.x + q.z * kt2.x + q.w * kt3.x;
        sacc[r][1] += q.x * kt0.y + q.y * kt1.y + q.z * kt2.y + q.w * kt3.y;
        sacc[r][2] += q.x * kt0.z + q.y * kt1.z + q.z * kt2.z + q.w * kt3.z;
        sacc[r][3] += q.x * kt0.w + q.y * kt1.w + q.z * kt2.w + q.w * kt3.w;
      }
    }
#pragma unroll
    for (int r = 0; r < NQR; ++r)
#pragma unroll
      for (int j = 0; j < 4; ++j) sacc[r][j] *= scale;
    // ---- softmax (per output row, over 1024 keys) ----
    float mA[4], invA[4], mB[4], invB[4];
    {
      float4 p = make_float4(hmax4a(sacc[0]), hmax4a(sacc[1]), hmax4a(sacc[2]),
                             hmax4a(sacc[3]));
      const float4 m = block_max4(p, red4);
      mA[0] = m.x; mA[1] = m.y; mA[2] = m.z; mA[3] = m.w;
    }
    if constexpr (NKV == 2) {
      float4 p = make_float4(hmax4a(sacc[4]), hmax4a(sacc[5]), hmax4a(sacc[6]),
                             hmax4a(sacc[7]));
      const float4 m = block_max4(p, red4);
      mB[0] = m.x; mB[1] = m.y; mB[2] = m.z; mB[3] = m.w;
    }
#pragma unroll
    for (int r = 0; r < NQR; ++r) {
      const float m = (r < 4) ? mA[r & 3] : mB[r & 3];
#pragma unroll
      for (int j = 0; j < 4; ++j) sacc[r][j] = __expf(sacc[r][j] - m);
    }
    {
      float4 p = make_float4(hsum4a(sacc[0]), hsum4a(sacc[1]), hsum4a(sacc[2]),
                             hsum4a(sacc[3]));
      const float4 sm = block_sum4(p, red4);
      invA[0] = 1.f / sm.x; invA[1] = 1.f / sm.y;
      invA[2] = 1.f / sm.z; invA[3] = 1.f / sm.w;
    }
    if constexpr (NKV == 2) {
      float4 p = make_float4(hsum4a(sacc[4]), hsum4a(sacc[5]), hsum4a(sacc[6]),
                             hsum4a(sacc[7]));
      const float4 sm = block_sum4(p, red4);
      invB[0] = 1.f / sm.x; invB[1] = 1.f / sm.y;
      invB[2] = 1.f / sm.z; invB[3] = 1.f / sm.w;
    }
    // ---- combined weights into sc4 ----
#pragma unroll
    for (int j = 0; j < 4; ++j) {
      float4 wv;
      if constexpr (NKV == 2) {
        wv.x = sacc[0][j] * invA[0] + sacc[4][j] * invB[0];
        wv.y = sacc[1][j] * invA[1] + sacc[5][j] * invB[1];
        wv.z = sacc[2][j] * invA[2] + sacc[6][j] * invB[2];
        wv.w = sacc[3][j] * invA[3] + sacc[7][j] * invB[3];
      } else {
        wv.x = sacc[0][j] * invA[0];
        wv.y = sacc[1][j] * invA[1];
        wv.z = sacc[2][j] * invA[2];
        wv.w = sacc[3][j] * invA[3];
      }
      sc4[4 * tid + j] = wv;
    }
    __syncthreads();
    // ---- phase 2: out += P V; keys over 4 kg groups, dims over 64 lanes ----
    const float* V0p = V + rowb * ldv + colo + dg * DPT;
#pragma unroll 4
    for (int u = 0; u < 256; ++u) {
      const int k = kg * 256 + u;
      const float4 p = sc4[k];
      if constexpr (DPT == 4) {
        const float4 v4 = *(const float4*)(V0p + (size_t)k * ldv);
        oacc[0][0] += p.x * v4.x; oacc[0][1] += p.x * v4.y;
        oacc[0][2] += p.x * v4.z; oacc[0][3] += p.x * v4.w;
        oacc[1][0] += p.y * v4.x; oacc[1][1] += p.y * v4.y;
        oacc[1][2] += p.y * v4.z; oacc[1][3] += p.y * v4.w;
        oacc[2][0] += p.z * v4.x; oacc[2][1] += p.z * v4.y;
        oacc[2][2] += p.z * v4.z; oacc[2][3] += p.z * v4.w;
        oacc[3][0] += p.w * v4.x; oacc[3][1] += p.w * v4.y;
        oacc[3][2] += p.w * v4.z; oacc[3][3] += p.w * v4.w;
      } else {
        const float2 v2 = *(const float2*)(V0p + (size_t)k * ldv);
        oacc[0][0] += p.x * v2.x; oacc[0][1] += p.x * v2.y;
        oacc[1][0] += p.y * v2.x; oacc[1][1] += p.y * v2.y;
        oacc[2][0] += p.z * v2.x; oacc[2][1] += p.z * v2.y;
        oacc[3][0] += p.w * v2.x; oacc[3][1] += p.w * v2.y;
      }
    }
  }
  // ---- cross-key-group reduction + bf16 store ----
#pragma unroll
  for (int qt = 0; qt < QT; ++qt) {
    __syncthreads();
#pragma unroll
    for (int j = 0; j < DPT; ++j) accsh[kg][dg * DPT + j] = oacc[qt][j];
    __syncthreads();
    if (kg == 0) {
      unsigned short* Rr = R + (rowb + qb * QT + qt) * 512 + colo + dg * DPT;
      float v[DPT];
#pragma unroll
      for (int j = 0; j < DPT; ++j)
        v[j] = (accsh[0][dg * DPT + j] + accsh[1][dg * DPT + j] +
                accsh[2][dg * DPT + j] + accsh[3][dg * DPT + j]) * post_scale;
      if constexpr (DPT == 4) {
        uint2 u;
        u.x = (unsigned)f2b(v[0]) | ((unsigned)f2b(v[1]) << 16);
        u.y = (unsigned)f2b(v[2]) | ((unsigned)f2b(v[3]) << 16);
        *(uint2*)Rr = u;
      } else {
        *(unsigned*)Rr = (unsigned)f2b(v[0]) | ((unsigned)f2b(v[1]) << 16);
      }
    }
  }
}

// ------------- out = LayerNorm(G + res) * g + b  (f32 out + optional bf16 out) ----
__global__ __launch_bounds__(256) void ln_kernel(
    const float* __restrict__ G, const float* __restrict__ res,
    const float* __restrict__ g, const float* __restrict__ b,
    float* __restrict__ out, unsigned short* __restrict__ outb) {
  __shared__ float sh[4];
  const int row = blockIdx.x, tid = threadIdx.x;
  const size_t off = (size_t)row * 512;
  const float x0 = G[off + tid] + res[off + tid];
  const float x1 = G[off + tid + 256] + res[off + tid + 256];
  const float mean = block_sum1(x0 + x1, sh) * (1.0f / 512.0f);
  const float d0 = x0 - mean, d1 = x1 - mean;
  const float var = block_sum1(d0 * d0 + d1 * d1, sh) * (1.0f / 512.0f);
  const float inv = rsqrtf(var + 1e-5f);
  const float y0 = d0 * inv * g[tid] + b[tid];
  const float y1 = d1 * inv * g[tid + 256] + b[tid + 256];
  out[off + tid] = y0;
  out[off + tid + 256] = y1;
  if (outb) {
    outb[off + tid] = f2b(y0);
    outb[off + tid + 256] = f2b(y1);
  }
}

extern "C" void kernel_launch(void* const* d_in, const int* in_sizes, int n_in,
                              void* d_out, int out_size, void* d_ws, size_t ws_size,
                              hipStream_t stream) {
  typedef unsigned short ushort_t;
  const float* cx   = (const float*)d_in[0];
  const float* cy   = (const float*)d_in[1];
  const float* txp  = (const float*)d_in[2];
  const float* in_W = (const float*)d_in[3];
  const float* in_b = (const float*)d_in[4];
  const float* cx_W = (const float*)d_in[5];
  const float* cx_b = (const float*)d_in[6];
  const float* tx_W = (const float*)d_in[7];
  const float* tx_b = (const float*)d_in[8];
  const float* sWk  = (const float*)d_in[9];
  const float* sWv  = (const float*)d_in[10];
  const float* sWq  = (const float*)d_in[11];
  const float* sWf  = (const float*)d_in[12];
  const float* sbf  = (const float*)d_in[13];
  const float* sg   = (const float*)d_in[14];
  const float* sb   = (const float*)d_in[15];
  const float* aWk  = (const float*)d_in[16];
  const float* aWv  = (const float*)d_in[17];
  const float* aWq  = (const float*)d_in[18];
  const float* aWf  = (const float*)d_in[19];
  const float* abf  = (const float*)d_in[20];
  const float* ag   = (const float*)d_in[21];
  const float* ab   = (const float*)d_in[22];

  const size_t MB = 1024 * 1024;
  char* ws = (char*)d_ws;
  float*    E     = (float*)(ws + 0 * MB);       // 8 MB
  ushort_t* Ebf   = (ushort_t*)(ws + 8 * MB);    // 4 MB
  float*    QA    = (float*)(ws + 12 * MB);      // 8 MB
  ushort_t* QAbf  = (ushort_t*)(ws + 20 * MB);   // 4 MB
  ushort_t* Rbbf  = (ushort_t*)(ws + 24 * MB);   // 4 MB
  float*    KVQ   = (float*)(ws + 28 * MB);      // 24 MB [4096][1536] K|V|Q
  float*    cK    = (float*)(ws + 52 * MB);      // 8 MB (G alias after ktrans)
  float*    cV    = (float*)(ws + 60 * MB);      // 8 MB
  float*    cQ    = (float*)(ws + 68 * MB);      // 8 MB
  float*    G     = cK;
  ushort_t* KtA   = (ushort_t*)(ws + 76 * MB);   // 4 MB bf16 [B][nh][D][1024]
  ushort_t* KtB   = (ushort_t*)(ws + 80 * MB);   // 4 MB
  ushort_t* Wkvqt[2] = {(ushort_t*)(ws + 84 * MB), (ushort_t*)(ws + 86 * MB)};
  ushort_t* Wft[2]   = {(ushort_t*)(ws + 88 * MB), (ushort_t*)(ws + 89 * MB)};
  ushort_t* aWvt[2]  = {(ushort_t*)(ws + 90 * MB), (ushort_t*)(ws + 91 * MB)};
  ushort_t* aWqt1    = (ushort_t*)(ws + 92 * MB);
  ushort_t* aWft[2]  = {(ushort_t*)(ws + 93 * MB), (ushort_t*)(ws + 94 * MB)};
  float*    Ttab     = (float*)(ws + 95 * MB);

  float* T_sc[2][3];
  for (int i = 0; i < 2; ++i)
    for (int w = 0; w < 3; ++w) T_sc[i][w] = Ttab + (size_t)(i * 3 + w) * 2048;
  float* T_cak[2] = {Ttab + 12288, Ttab + 12288 + 1024};
  float* T_caq0 = Ttab + 14336;

  const dim3 tb(32, 8);
  const dim3 tg512(16, 16), tg1024(16, 32);

  // ---- prep: weight transposes + projection tables ----
  for (int i = 0; i < 2; ++i) {
    transpose_bf_kernel<<<tg512, tb, 0, stream>>>(sWk + (size_t)i * 262144, Wkvqt[i], 512, 512);
    transpose_bf_kernel<<<tg512, tb, 0, stream>>>(sWv + (size_t)i * 262144, Wkvqt[i] + 512 * 512, 512, 512);
    transpose_bf_kernel<<<tg512, tb, 0, stream>>>(sWq + (size_t)i * 262144, Wkvqt[i] + 1024 * 512, 512, 512);
    transpose_bf_kernel<<<tg1024, tb, 0, stream>>>(sWf + (size_t)i * 524288, Wft[i], 1024, 512);
    transpose_bf_kernel<<<tg512, tb, 0, stream>>>(aWv + (size_t)i * 262144, aWvt[i], 512, 512);
    transpose_bf_kernel<<<tg1024, tb, 0, stream>>>(aWf + (size_t)i * 524288, aWft[i], 1024, 512);
    tabproj_kernel<<<512, 256, 0, stream>>>(in_W, in_b, sWk + (size_t)i * 262144, T_sc[i][0], 3);
    tabproj_kernel<<<512, 256, 0, stream>>>(in_W, in_b, sWv + (size_t)i * 262144, T_sc[i][1], 3);
    tabproj_kernel<<<512, 256, 0, stream>>>(in_W, in_b, sWq + (size_t)i * 262144, T_sc[i][2], 3);
    tabproj_kernel<<<512, 256, 0, stream>>>(cx_W, cx_b, aWk + (size_t)i * 262144, T_cak[i], 1);
  }
  transpose_bf_kernel<<<tg512, tb, 0, stream>>>(aWq + 262144, aWqt1, 512, 512);
  tabproj_kernel<<<512, 256, 0, stream>>>(tx_W, tx_b, aWq, T_caq0, 1);

  // ---- initial activations ----
  affine3_kernel<<<4096, 512, 0, stream>>>(cx, cy, 0, in_W, in_b, E, Ebf);
  rank1_kernel<<<4096, 512, 0, stream>>>(txp, tx_W, tx_b, QA, QAbf);

  // ---- 8 self/cross encoder layers ----
  for (int p = 0; p < 4; ++p) {
    for (int i = 0; i < 2; ++i) {
      gemm_mfma_kernel<<<dim3(24, 32), 256, 0, stream>>>(Ebf, 512, nullptr, 0, Wkvqt[i],
                                                         nullptr, KVQ, 4096, 1536);
      ktrans_kernel<<<dim3(32, 8, 8), tb, 0, stream>>>(KVQ, 1536, 2, 256, KtA);
      if (p > 0) {
        affine3_kernel<<<4096, 512, 0, stream>>>(cx, cy, p, T_sc[i][0], T_sc[i][0] + 1536, cK, nullptr);
        affine3_kernel<<<4096, 512, 0, stream>>>(cx, cy, p, T_sc[i][1], T_sc[i][1] + 1536, cV, nullptr);
        affine3_kernel<<<4096, 512, 0, stream>>>(cx, cy, p, T_sc[i][2], T_sc[i][2] + 1536, cQ, nullptr);
        ktrans_kernel<<<dim3(32, 8, 8), tb, 0, stream>>>(cK, 512, 2, 256, KtB);
        attn2_kernel<256, 2><<<2048, 256, 0, stream>>>(
            KVQ + 1024, cQ, KtA, KtB, KVQ + 512, cV, 1536, 512, 1536, 512,
            1.0f, 0.0625f, 2, Rbbf);
      } else {
        // x2 is x: 4 identical sdpa terms -> 4 * sdpa(sQ,sK,sV)
        attn2_kernel<256, 1><<<2048, 256, 0, stream>>>(
            KVQ + 1024, KVQ + 1024, KtA, KtA, KVQ + 512, KVQ + 512,
            1536, 1536, 1536, 1536, 4.0f, 0.0625f, 2, Rbbf);
      }
      gemm_mfma_kernel<<<dim3(8, 32), 256, 0, stream>>>(Ebf, 512, Rbbf, 512, Wft[i],
                                                        sbf + (size_t)i * 512, G, 4096, 512);
      ln_kernel<<<4096, 256, 0, stream>>>(G, E, sg + (size_t)i * 512, sb + (size_t)i * 512,
                                          E, Ebf);
    }
  }

  // ---- 2 cross-attention decoder layers ----
  for (int i = 0; i < 2; ++i) {
    rank1_kernel<<<4096, 512, 0, stream>>>(cx, T_cak[i], T_cak[i] + 512, cK, nullptr);
    ktrans_kernel<<<dim3(32, 4, 16), tb, 0, stream>>>(cK, 512, 4, 128, KtA);
    gemm_mfma_kernel<<<dim3(8, 32), 256, 0, stream>>>(Ebf, 512, nullptr, 0, aWvt[i],
                                                      nullptr, cV, 4096, 512);
    if (i == 0)
      rank1_kernel<<<4096, 512, 0, stream>>>(txp, T_caq0, T_caq0 + 512, cQ, nullptr);
    else
      gemm_mfma_kernel<<<dim3(8, 32), 256, 0, stream>>>(QAbf, 512, nullptr, 0, aWqt1,
                                                        nullptr, cQ, 4096, 512);
    attn2_kernel<128, 1><<<4096, 256, 0, stream>>>(
        cQ, cQ, KtA, KtA, cV, cV, 512, 512, 512, 512,
        1.0f, 0.08838834764831845f, 4, Rbbf);
    gemm_mfma_kernel<<<dim3(8, 32), 256, 0, stream>>>(QAbf, 512, Rbbf, 512, aWft[i],
                                                      abf + (size_t)i * 512, G, 4096, 512);
    ln_kernel<<<4096, 256, 0, stream>>>(G, QA, ag + (size_t)i * 512, ab + (size_t)i * 512,
                                        (i == 1) ? (float*)d_out : QA,
                                        (i == 1) ? nullptr : QAbf);
  }
  (void)in_sizes; (void)n_in; (void)out_size; (void)ws_size;
}

// Round 6
// 1903.898 us; speedup vs baseline: 9.9603x; 2.1201x over previous
//
#include <hip/hip_runtime.h>

#define DEVINL __device__ __forceinline__

typedef short bf16x8 __attribute__((ext_vector_type(8)));
typedef float f32x4 __attribute__((ext_vector_type(4)));

DEVINL unsigned short f2b(float f) {  // f32 -> bf16 (round to nearest even)
  unsigned u = __float_as_uint(f);
  u = (u + 0x7FFFu + ((u >> 16) & 1u)) >> 16;
  return (unsigned short)u;
}

// ---------------- reduction helpers ----------------
DEVINL float4 block_sum4(float4 v, float4* sh) {
  const int lane = threadIdx.x & 63, wid = threadIdx.x >> 6;
#pragma unroll
  for (int o = 32; o; o >>= 1) {
    v.x += __shfl_down(v.x, o);
    v.y += __shfl_down(v.y, o);
    v.z += __shfl_down(v.z, o);
    v.w += __shfl_down(v.w, o);
  }
  __syncthreads();
  if (lane == 0) sh[wid] = v;
  __syncthreads();
  float4 a = sh[0], b = sh[1], c = sh[2], d = sh[3], r;
  r.x = a.x + b.x + c.x + d.x;
  r.y = a.y + b.y + c.y + d.y;
  r.z = a.z + b.z + c.z + d.z;
  r.w = a.w + b.w + c.w + d.w;
  return r;
}
DEVINL float block_sum1(float v, float* sh) {
  const int lane = threadIdx.x & 63, wid = threadIdx.x >> 6;
#pragma unroll
  for (int o = 32; o; o >>= 1) v += __shfl_down(v, o);
  __syncthreads();
  if (lane == 0) sh[wid] = v;
  __syncthreads();
  return sh[0] + sh[1] + sh[2] + sh[3];
}

// ---- table projection: P[v,j] = V[v,:] @ W[:,j], P[nvec,j] = bias @ W[:,j] ----
__global__ __launch_bounds__(256) void tabproj_kernel(
    const float* __restrict__ V, const float* __restrict__ bias,
    const float* __restrict__ W, float* __restrict__ P, int nvec) {
  __shared__ float4 sh4[4];
  const int j = blockIdx.x, tid = threadIdx.x;
  float acc[4] = {0.f, 0.f, 0.f, 0.f};
  for (int kk = tid; kk < 512; kk += 256) {
    const float w = W[(size_t)kk * 512 + j];
    for (int v = 0; v < nvec; ++v) acc[v] += V[(size_t)v * 512 + kk] * w;
    acc[3] += bias[kk] * w;
  }
  float4 packed = make_float4(acc[0], acc[1], acc[2], acc[3]);
  packed = block_sum4(packed, sh4);
  if (tid == 0) {
    const float vals[4] = {packed.x, packed.y, packed.z, packed.w};
    for (int v = 0; v < nvec; ++v) P[(size_t)v * 512 + j] = vals[v];
    P[(size_t)nvec * 512 + j] = vals[3];
  }
}

// ---- weight prep: src f32 [K][N] -> dst bf16 [N][K] ----
__global__ __launch_bounds__(256) void transpose_bf_kernel(
    const float* __restrict__ src, unsigned short* __restrict__ dst, int K, int N) {
  __shared__ float tile[32][33];
  const int n0 = blockIdx.x * 32, k0 = blockIdx.y * 32;
  const int tx = threadIdx.x, ty = threadIdx.y;  // 32 x 8
#pragma unroll
  for (int r = 0; r < 4; ++r)
    tile[ty + 8 * r][tx] = src[(size_t)(k0 + ty + 8 * r) * N + n0 + tx];
  __syncthreads();
#pragma unroll
  for (int r = 0; r < 4; ++r)
    dst[(size_t)(n0 + ty + 8 * r) * K + k0 + tx] = f2b(tile[tx][ty + 8 * r]);
}

// ---- K bf16 pack: K f32 [b*1024][ld] (head cols at h*D) -> Kbf [b][h][1024][D] ----
__global__ __launch_bounds__(512) void kbf_kernel(
    const float* __restrict__ K, int ld, int nh, int D,
    unsigned short* __restrict__ Kbf) {
  const int row = blockIdx.x;           // b*1024 + s
  const int b = row >> 10, s = row & 1023;
  const int j = threadIdx.x;            // 0..511 = h*D + d
  const int h = j / D, d = j - h * D;
  Kbf[(((size_t)(b * nh + h) * 1024) + s) * D + d] = f2b(K[(size_t)row * ld + h * D + d]);
}

// ---- V transpose: V f32 [b*1024][ld] (head cols at h*D) -> Vt bf16 [b][h][D][1024] ----
__global__ __launch_bounds__(256) void ktrans_kernel(
    const float* __restrict__ K, int ld, int nh, int D,
    unsigned short* __restrict__ Kt) {
  __shared__ float tile[32][33];
  const int s0 = blockIdx.x * 32, d0 = blockIdx.y * 32;
  const int b = blockIdx.z / nh, h = blockIdx.z % nh;
  const int tx = threadIdx.x, ty = threadIdx.y;  // 32 x 8
  const float* src = K + ((size_t)b * 1024 + s0) * ld + h * D + d0;
#pragma unroll
  for (int r = 0; r < 4; ++r)
    tile[ty + 8 * r][tx] = src[(size_t)(ty + 8 * r) * ld + tx];  // [s][d]
  __syncthreads();
  unsigned short* dst = Kt + ((size_t)(b * nh + h) * D + d0) * 1024 + s0;
#pragma unroll
  for (int r = 0; r < 4; ++r)
    dst[(size_t)(ty + 8 * r) * 1024 + tx] = f2b(tile[tx][ty + 8 * r]);  // [d][s]
}

// ---- out[r,:] = cx[r]*W3[0,:] + y0*W3[1,:] + y1*W3[2,:] + bias ----
__global__ __launch_bounds__(512) void affine3_kernel(
    const float* __restrict__ cx, const float* __restrict__ cy, int sel,
    const float* __restrict__ W3, const float* __restrict__ bias,
    float* __restrict__ out, unsigned short* __restrict__ outb) {
  const int r = blockIdx.x, j = threadIdx.x;
  const float* y = cy + (size_t)r * 8 + 2 * sel;
  const float v = cx[r] * W3[j] + y[0] * W3[512 + j] + y[1] * W3[1024 + j] + bias[j];
  if (out) out[(size_t)r * 512 + j] = v;
  if (outb) outb[(size_t)r * 512 + j] = f2b(v);
}

// ---- out[r,:] = x[r]*w + b ----
__global__ __launch_bounds__(512) void rank1_kernel(
    const float* __restrict__ x, const float* __restrict__ w,
    const float* __restrict__ b, float* __restrict__ out,
    unsigned short* __restrict__ outb) {
  const int r = blockIdx.x, j = threadIdx.x;
  const float v = x[r] * w[j] + b[j];
  if (out) out[(size_t)r * 512 + j] = v;
  if (outb) outb[(size_t)r * 512 + j] = f2b(v);
}

// ---------------- MFMA GEMM: C = [A0 | A1] @ Wt^T (+bias), bf16 in, f32 out ------
__global__ __launch_bounds__(256) void gemm_mfma_kernel(
    const unsigned short* __restrict__ A0, int K0,
    const unsigned short* __restrict__ A1, int K1,
    const unsigned short* __restrict__ Wt, const float* __restrict__ bias,
    float* __restrict__ C, int M, int N) {
  constexpr int BM = 128, BN = 64, BK = 32, LDP = 40;
  __shared__ unsigned short As[BM * LDP];
  __shared__ unsigned short Bs[BN * LDP];
  const int tid = threadIdx.x;
  const int lane = tid & 63, w = tid >> 6;
  const int bm = blockIdx.y * BM, bn = blockIdx.x * BN;
  const int wm = (w & 1) * 64, wn = (w >> 1) * 32;
  const int l15 = lane & 15, lq = lane >> 4;
  const int ar = tid >> 1, ac = (tid & 1) * 16;
  const int br = tid >> 2, bc = (tid & 3) * 8;
  const int Ktot = K0 + K1;
  f32x4 acc[4][2] = {};
  for (int k0 = 0; k0 < Ktot; k0 += BK) {
    const unsigned short* A;
    int kk, Ak;
    if (k0 < K0) { A = A0; kk = k0;      Ak = K0; }
    else         { A = A1; kk = k0 - K0; Ak = K1; }
    const uint4 a0 = *(const uint4*)(A + (size_t)(bm + ar) * Ak + kk + ac);
    const uint4 a1 = *(const uint4*)(A + (size_t)(bm + ar) * Ak + kk + ac + 8);
    const uint4 b0 = *(const uint4*)(Wt + (size_t)(bn + br) * Ktot + k0 + bc);
    __syncthreads();
    *(uint4*)(As + ar * LDP + ac) = a0;
    *(uint4*)(As + ar * LDP + ac + 8) = a1;
    *(uint4*)(Bs + br * LDP + bc) = b0;
    __syncthreads();
    bf16x8 af[4], bfr[2];
#pragma unroll
    for (int mt = 0; mt < 4; ++mt)
      af[mt] = *(const bf16x8*)(As + (wm + mt * 16 + l15) * LDP + lq * 8);
#pragma unroll
    for (int nt = 0; nt < 2; ++nt)
      bfr[nt] = *(const bf16x8*)(Bs + (wn + nt * 16 + l15) * LDP + lq * 8);
#pragma unroll
    for (int mt = 0; mt < 4; ++mt)
#pragma unroll
      for (int nt = 0; nt < 2; ++nt)
        acc[mt][nt] =
            __builtin_amdgcn_mfma_f32_16x16x32_bf16(af[mt], bfr[nt], acc[mt][nt], 0, 0, 0);
  }
#pragma unroll
  for (int nt = 0; nt < 2; ++nt) {
    const int col = bn + wn + nt * 16 + l15;
    const float bv = bias ? bias[col] : 0.f;
#pragma unroll
    for (int mt = 0; mt < 4; ++mt) {
#pragma unroll
      for (int r = 0; r < 4; ++r) {
        const int row = bm + wm + mt * 16 + lq * 4 + r;
        C[(size_t)row * N + col] = acc[mt][nt][r] + bv;
      }
    }
  }
}

// ---------------- MFMA flash attention ----------------
// Block = 16 Q rows of one (b,head); 4 waves own 256 keys each.
// Output rows q: sum over sides s of [softmax(Qa_q Ks^T)+softmax(Qb_q Ks^T)] Vs
// (NKV=1: single sdpa with Qa only.) R bf16, row stride 512, scaled by post_scale.
// Kbf: [b][h][1024][D] bf16; Vt: [b][h][D][1024] bf16.
template <int D, int NKV>
__global__ __launch_bounds__(256, 2) void attn_mfma_kernel(
    const float* __restrict__ Qa, const float* __restrict__ Qb, int ldqa, int ldqb,
    const unsigned short* __restrict__ KbfA, const unsigned short* __restrict__ KbfB,
    const unsigned short* __restrict__ VtA, const unsigned short* __restrict__ VtB,
    float post_scale, float scale, int nh, unsigned short* __restrict__ R) {
  constexpr int NQS = NKV;         // Q streams
  constexpr int QP = D + 8;        // q LDS pitch (2-way-free)
  constexpr int WP = 1024 + 8;     // weight strip pitch
  constexpr int DT = D / 64;       // PV d-tiles per wave
  const int tid = threadIdx.x;
  const int lane = tid & 63, w = tid >> 6;
  const int l15 = lane & 15, lq = lane >> 4;
  const int nbh = 4 * nh;
  const int bh = blockIdx.x % nbh;          // XCD-local (b,h)
  const int qb16 = (blockIdx.x / nbh) * 16; // q-row window
  const int b = bh / nh, head = bh % nh;
  const size_t rowb = (size_t)b * 1024;
  const int colo = head * D;

  __shared__ unsigned short qsh[NQS * 16 * QP];
  __shared__ unsigned short wsh[16 * WP];
  __shared__ float redA[4][16];
  __shared__ float redB[4][16];

  // ---- stage Q tiles as bf16 ----
  for (int idx = tid; idx < NQS * 16 * D; idx += 256) {
    const int st = idx / (16 * D);
    const int rem = idx - st * 16 * D;
    const int r = rem / D, d = rem - r * D;
    const float* Q = st ? Qb : Qa;
    const int ldq = st ? ldqb : ldqa;
    qsh[st * 16 * QP + r * QP + d] = f2b(Q[(rowb + qb16 + r) * (size_t)ldq + colo + d]);
  }
  __syncthreads();

  f32x4 acc_o[DT] = {};

  for (int s = 0; s < NKV; ++s) {
    const unsigned short* Kb = (s ? KbfB : KbfA) + (size_t)bh * 1024 * D;
    const unsigned short* Vtb = (s ? VtB : VtA) + (size_t)bh * D * 1024;
    // ---- QK^T: scores in C-layout regs (row=lq*4+r -> q, col=l15 -> key) ----
    f32x4 acc[NQS][16] = {};
#pragma unroll 1
    for (int kc = 0; kc < D / 32; ++kc) {
      const bf16x8 qa = *(const bf16x8*)(qsh + l15 * QP + kc * 32 + lq * 8);
      bf16x8 qb2;
      if constexpr (NKV == 2)
        qb2 = *(const bf16x8*)(qsh + 16 * QP + l15 * QP + kc * 32 + lq * 8);
#pragma unroll
      for (int st = 0; st < 16; ++st) {
        const int srow = w * 256 + st * 16 + l15;
        const bf16x8 kf = *(const bf16x8*)(Kb + (size_t)srow * D + kc * 32 + lq * 8);
        acc[0][st] = __builtin_amdgcn_mfma_f32_16x16x32_bf16(qa, kf, acc[0][st], 0, 0, 0);
        if constexpr (NKV == 2)
          acc[1][st] = __builtin_amdgcn_mfma_f32_16x16x32_bf16(qb2, kf, acc[1][st], 0, 0, 0);
      }
    }
#pragma unroll
    for (int st = 0; st < 16; ++st) {
      acc[0][st] *= scale;
      if constexpr (NKV == 2) acc[1][st] *= scale;
    }
    // ---- row max (per stream) ----
    float pmA[4], pmB[4];
#pragma unroll
    for (int r = 0; r < 4; ++r) { pmA[r] = -3e38f; pmB[r] = -3e38f; }
#pragma unroll
    for (int st = 0; st < 16; ++st)
#pragma unroll
      for (int r = 0; r < 4; ++r) {
        pmA[r] = fmaxf(pmA[r], acc[0][st][r]);
        if constexpr (NKV == 2) pmB[r] = fmaxf(pmB[r], acc[1][st][r]);
      }
#pragma unroll
    for (int o = 1; o < 16; o <<= 1)
#pragma unroll
      for (int r = 0; r < 4; ++r) {
        pmA[r] = fmaxf(pmA[r], __shfl_xor(pmA[r], o));
        if constexpr (NKV == 2) pmB[r] = fmaxf(pmB[r], __shfl_xor(pmB[r], o));
      }
    __syncthreads();  // wsh/red safe from previous side's readers
    if (l15 == 0) {
#pragma unroll
      for (int r = 0; r < 4; ++r) {
        redA[w][lq * 4 + r] = pmA[r];
        if constexpr (NKV == 2) redB[w][lq * 4 + r] = pmB[r];
      }
    }
    __syncthreads();
    float mA[4], mB[4];
#pragma unroll
    for (int r = 0; r < 4; ++r) {
      mA[r] = fmaxf(fmaxf(redA[0][lq * 4 + r], redA[1][lq * 4 + r]),
                    fmaxf(redA[2][lq * 4 + r], redA[3][lq * 4 + r]));
      if constexpr (NKV == 2)
        mB[r] = fmaxf(fmaxf(redB[0][lq * 4 + r], redB[1][lq * 4 + r]),
                      fmaxf(redB[2][lq * 4 + r], redB[3][lq * 4 + r]));
    }
    // ---- exp + row sum ----
    float psA[4] = {0.f, 0.f, 0.f, 0.f}, psB[4] = {0.f, 0.f, 0.f, 0.f};
#pragma unroll
    for (int st = 0; st < 16; ++st)
#pragma unroll
      for (int r = 0; r < 4; ++r) {
        acc[0][st][r] = __expf(acc[0][st][r] - mA[r]);
        psA[r] += acc[0][st][r];
        if constexpr (NKV == 2) {
          acc[1][st][r] = __expf(acc[1][st][r] - mB[r]);
          psB[r] += acc[1][st][r];
        }
      }
#pragma unroll
    for (int o = 1; o < 16; o <<= 1)
#pragma unroll
      for (int r = 0; r < 4; ++r) {
        psA[r] += __shfl_xor(psA[r], o);
        if constexpr (NKV == 2) psB[r] += __shfl_xor(psB[r], o);
      }
    __syncthreads();  // all done reading redA/redB maxes
    if (l15 == 0) {
#pragma unroll
      for (int r = 0; r < 4; ++r) {
        redA[w][lq * 4 + r] = psA[r];
        if constexpr (NKV == 2) redB[w][lq * 4 + r] = psB[r];
      }
    }
    __syncthreads();
    float invA[4], invB[4];
#pragma unroll
    for (int r = 0; r < 4; ++r) {
      invA[r] = 1.f / (redA[0][lq * 4 + r] + redA[1][lq * 4 + r] +
                       redA[2][lq * 4 + r] + redA[3][lq * 4 + r]);
      if constexpr (NKV == 2)
        invB[r] = 1.f / (redB[0][lq * 4 + r] + redB[1][lq * 4 + r] +
                         redB[2][lq * 4 + r] + redB[3][lq * 4 + r]);
    }
    // ---- combined weight strip (bf16, A-operand layout) ----
#pragma unroll
    for (int st = 0; st < 16; ++st)
#pragma unroll
      for (int r = 0; r < 4; ++r) {
        float wv = acc[0][st][r] * invA[r];
        if constexpr (NKV == 2) wv += acc[1][st][r] * invB[r];
        wsh[(lq * 4 + r) * WP + w * 256 + st * 16 + l15] = f2b(wv);
      }
    __syncthreads();
    // ---- PV: out[q][d] += W[q][s] Vt[d][s] ----
#pragma unroll 2
    for (int sc = 0; sc < 32; ++sc) {
      const bf16x8 pa = *(const bf16x8*)(wsh + l15 * WP + sc * 32 + lq * 8);
#pragma unroll
      for (int dt = 0; dt < DT; ++dt) {
        const int drow = w * (DT * 16) + dt * 16 + l15;
        const bf16x8 vb = *(const bf16x8*)(Vtb + (size_t)drow * 1024 + sc * 32 + lq * 8);
        acc_o[dt] = __builtin_amdgcn_mfma_f32_16x16x32_bf16(pa, vb, acc_o[dt], 0, 0, 0);
      }
    }
  }
  // ---- epilogue: C layout row=lq*4+r -> q, col=l15 -> d ----
#pragma unroll
  for (int dt = 0; dt < DT; ++dt)
#pragma unroll
    for (int r = 0; r < 4; ++r) {
      const int q = lq * 4 + r;
      const int d = w * (DT * 16) + dt * 16 + l15;
      R[(rowb + qb16 + q) * 512 + colo + d] = f2b(acc_o[dt][r] * post_scale);
    }
}

// ------------- out = LayerNorm(G + res) * g + b  (f32 out + optional bf16 out) ----
__global__ __launch_bounds__(256) void ln_kernel(
    const float* __restrict__ G, const float* __restrict__ res,
    const float* __restrict__ g, const float* __restrict__ b,
    float* __restrict__ out, unsigned short* __restrict__ outb) {
  __shared__ float sh[4];
  const int row = blockIdx.x, tid = threadIdx.x;
  const size_t off = (size_t)row * 512;
  const float x0 = G[off + tid] + res[off + tid];
  const float x1 = G[off + tid + 256] + res[off + tid + 256];
  const float mean = block_sum1(x0 + x1, sh) * (1.0f / 512.0f);
  const float d0 = x0 - mean, d1 = x1 - mean;
  const float var = block_sum1(d0 * d0 + d1 * d1, sh) * (1.0f / 512.0f);
  const float inv = rsqrtf(var + 1e-5f);
  const float y0 = d0 * inv * g[tid] + b[tid];
  const float y1 = d1 * inv * g[tid + 256] + b[tid + 256];
  out[off + tid] = y0;
  out[off + tid + 256] = y1;
  if (outb) {
    outb[off + tid] = f2b(y0);
    outb[off + tid + 256] = f2b(y1);
  }
}

extern "C" void kernel_launch(void* const* d_in, const int* in_sizes, int n_in,
                              void* d_out, int out_size, void* d_ws, size_t ws_size,
                              hipStream_t stream) {
  typedef unsigned short ushort_t;
  const float* cx   = (const float*)d_in[0];
  const float* cy   = (const float*)d_in[1];
  const float* txp  = (const float*)d_in[2];
  const float* in_W = (const float*)d_in[3];
  const float* in_b = (const float*)d_in[4];
  const float* cx_W = (const float*)d_in[5];
  const float* cx_b = (const float*)d_in[6];
  const float* tx_W = (const float*)d_in[7];
  const float* tx_b = (const float*)d_in[8];
  const float* sWk  = (const float*)d_in[9];
  const float* sWv  = (const float*)d_in[10];
  const float* sWq  = (const float*)d_in[11];
  const float* sWf  = (const float*)d_in[12];
  const float* sbf  = (const float*)d_in[13];
  const float* sg   = (const float*)d_in[14];
  const float* sb   = (const float*)d_in[15];
  const float* aWk  = (const float*)d_in[16];
  const float* aWv  = (const float*)d_in[17];
  const float* aWq  = (const float*)d_in[18];
  const float* aWf  = (const float*)d_in[19];
  const float* abf  = (const float*)d_in[20];
  const float* ag   = (const float*)d_in[21];
  const float* ab   = (const float*)d_in[22];

  const size_t MB = 1024 * 1024;
  char* ws = (char*)d_ws;
  float*    E     = (float*)(ws + 0 * MB);       // 8 MB
  ushort_t* Ebf   = (ushort_t*)(ws + 8 * MB);    // 4 MB
  float*    QA    = (float*)(ws + 12 * MB);      // 8 MB
  ushort_t* QAbf  = (ushort_t*)(ws + 20 * MB);   // 4 MB
  ushort_t* Rbbf  = (ushort_t*)(ws + 24 * MB);   // 4 MB
  float*    KVQ   = (float*)(ws + 28 * MB);      // 24 MB [4096][1536] K|V|Q
  float*    cK    = (float*)(ws + 52 * MB);      // 8 MB (G alias after kbf)
  float*    cV    = (float*)(ws + 60 * MB);      // 8 MB
  float*    cQ    = (float*)(ws + 68 * MB);      // 8 MB
  float*    G     = cK;
  ushort_t* KbfA  = (ushort_t*)(ws + 76 * MB);   // 4 MB [b][h][1024][D]
  ushort_t* VtA   = (ushort_t*)(ws + 80 * MB);   // 4 MB [b][h][D][1024]
  ushort_t* KbfB  = (ushort_t*)(ws + 84 * MB);   // 4 MB
  ushort_t* VtB   = (ushort_t*)(ws + 88 * MB);   // 4 MB
  ushort_t* Wkvqt[2] = {(ushort_t*)(ws + 92 * MB),
                        (ushort_t*)(ws + 92 * MB + 1536 * 1024)};  // 1.5 MB ea
  ushort_t* Wft[2]   = {(ushort_t*)(ws + 95 * MB), (ushort_t*)(ws + 96 * MB)};  // 1 MB ea
  ushort_t* aWvt[2]  = {(ushort_t*)(ws + 97 * MB),
                        (ushort_t*)(ws + 97 * MB + 512 * 1024)};   // 0.5 MB ea
  ushort_t* aWqt1    = (ushort_t*)(ws + 98 * MB);
  ushort_t* aWft[2]  = {(ushort_t*)(ws + 99 * MB), (ushort_t*)(ws + 100 * MB)};
  float*    Ttab     = (float*)(ws + 101 * MB);

  float* T_sc[2][3];
  for (int i = 0; i < 2; ++i)
    for (int w = 0; w < 3; ++w) T_sc[i][w] = Ttab + (size_t)(i * 3 + w) * 2048;
  float* T_cak[2] = {Ttab + 12288, Ttab + 12288 + 1024};
  float* T_caq0 = Ttab + 14336;

  const dim3 tb(32, 8);
  const dim3 tg512(16, 16), tg1024(16, 32);

  // ---- prep: weight transposes + projection tables ----
  for (int i = 0; i < 2; ++i) {
    transpose_bf_kernel<<<tg512, tb, 0, stream>>>(sWk + (size_t)i * 262144, Wkvqt[i], 512, 512);
    transpose_bf_kernel<<<tg512, tb, 0, stream>>>(sWv + (size_t)i * 262144, Wkvqt[i] + 512 * 512, 512, 512);
    transpose_bf_kernel<<<tg512, tb, 0, stream>>>(sWq + (size_t)i * 262144, Wkvqt[i] + 1024 * 512, 512, 512);
    transpose_bf_kernel<<<tg1024, tb, 0, stream>>>(sWf + (size_t)i * 524288, Wft[i], 1024, 512);
    transpose_bf_kernel<<<tg512, tb, 0, stream>>>(aWv + (size_t)i * 262144, aWvt[i], 512, 512);
    transpose_bf_kernel<<<tg1024, tb, 0, stream>>>(aWf + (size_t)i * 524288, aWft[i], 1024, 512);
    tabproj_kernel<<<512, 256, 0, stream>>>(in_W, in_b, sWk + (size_t)i * 262144, T_sc[i][0], 3);
    tabproj_kernel<<<512, 256, 0, stream>>>(in_W, in_b, sWv + (size_t)i * 262144, T_sc[i][1], 3);
    tabproj_kernel<<<512, 256, 0, stream>>>(in_W, in_b, sWq + (size_t)i * 262144, T_sc[i][2], 3);
    tabproj_kernel<<<512, 256, 0, stream>>>(cx_W, cx_b, aWk + (size_t)i * 262144, T_cak[i], 1);
  }
  transpose_bf_kernel<<<tg512, tb, 0, stream>>>(aWq + 262144, aWqt1, 512, 512);
  tabproj_kernel<<<512, 256, 0, stream>>>(tx_W, tx_b, aWq, T_caq0, 1);

  // ---- initial activations ----
  affine3_kernel<<<4096, 512, 0, stream>>>(cx, cy, 0, in_W, in_b, E, Ebf);
  rank1_kernel<<<4096, 512, 0, stream>>>(txp, tx_W, tx_b, QA, QAbf);

  // ---- 8 self/cross encoder layers ----
  for (int p = 0; p < 4; ++p) {
    for (int i = 0; i < 2; ++i) {
      gemm_mfma_kernel<<<dim3(24, 32), 256, 0, stream>>>(Ebf, 512, nullptr, 0, Wkvqt[i],
                                                         nullptr, KVQ, 4096, 1536);
      kbf_kernel<<<4096, 512, 0, stream>>>(KVQ, 1536, 2, 256, KbfA);
      ktrans_kernel<<<dim3(32, 8, 8), tb, 0, stream>>>(KVQ + 512, 1536, 2, 256, VtA);
      if (p > 0) {
        affine3_kernel<<<4096, 512, 0, stream>>>(cx, cy, p, T_sc[i][0], T_sc[i][0] + 1536, cK, nullptr);
        affine3_kernel<<<4096, 512, 0, stream>>>(cx, cy, p, T_sc[i][1], T_sc[i][1] + 1536, cV, nullptr);
        affine3_kernel<<<4096, 512, 0, stream>>>(cx, cy, p, T_sc[i][2], T_sc[i][2] + 1536, cQ, nullptr);
        kbf_kernel<<<4096, 512, 0, stream>>>(cK, 512, 2, 256, KbfB);
        ktrans_kernel<<<dim3(32, 8, 8), tb, 0, stream>>>(cV, 512, 2, 256, VtB);
        attn_mfma_kernel<256, 2><<<512, 256, 0, stream>>>(
            KVQ + 1024, cQ, 1536, 512, KbfA, KbfB, VtA, VtB, 1.0f, 0.0625f, 2, Rbbf);
      } else {
        // x2 is x: 4 identical sdpa terms -> 4 * sdpa(sQ,sK,sV)
        attn_mfma_kernel<256, 1><<<512, 256, 0, stream>>>(
            KVQ + 1024, KVQ + 1024, 1536, 1536, KbfA, KbfA, VtA, VtA, 4.0f, 0.0625f, 2, Rbbf);
      }
      gemm_mfma_kernel<<<dim3(8, 32), 256, 0, stream>>>(Ebf, 512, Rbbf, 512, Wft[i],
                                                        sbf + (size_t)i * 512, G, 4096, 512);
      ln_kernel<<<4096, 256, 0, stream>>>(G, E, sg + (size_t)i * 512, sb + (size_t)i * 512,
                                          E, Ebf);
    }
  }

  // ---- 2 cross-attention decoder layers ----
  for (int i = 0; i < 2; ++i) {
    rank1_kernel<<<4096, 512, 0, stream>>>(cx, T_cak[i], T_cak[i] + 512, cK, nullptr);
    kbf_kernel<<<4096, 512, 0, stream>>>(cK, 512, 4, 128, KbfA);
    gemm_mfma_kernel<<<dim3(8, 32), 256, 0, stream>>>(Ebf, 512, nullptr, 0, aWvt[i],
                                                      nullptr, cV, 4096, 512);
    ktrans_kernel<<<dim3(32, 4, 16), tb, 0, stream>>>(cV, 512, 4, 128, VtA);
    if (i == 0)
      rank1_kernel<<<4096, 512, 0, stream>>>(txp, T_caq0, T_caq0 + 512, cQ, nullptr);
    else
      gemm_mfma_kernel<<<dim3(8, 32), 256, 0, stream>>>(QAbf, 512, nullptr, 0, aWqt1,
                                                        nullptr, cQ, 4096, 512);
    attn_mfma_kernel<128, 1><<<1024, 256, 0, stream>>>(
        cQ, cQ, 512, 512, KbfA, KbfA, VtA, VtA, 1.0f, 0.08838834764831845f, 4, Rbbf);
    gemm_mfma_kernel<<<dim3(8, 32), 256, 0, stream>>>(QAbf, 512, Rbbf, 512, aWft[i],
                                                      abf + (size_t)i * 512, G, 4096, 512);
    ln_kernel<<<4096, 256, 0, stream>>>(G, QA, ag + (size_t)i * 512, ab + (size_t)i * 512,
                                        (i == 1) ? (float*)d_out : QA,
                                        (i == 1) ? nullptr : QAbf);
  }
  (void)in_sizes; (void)n_in; (void)out_size; (void)ws_size;
}

// Round 7
// 1484.913 us; speedup vs baseline: 12.7707x; 1.2822x over previous
//
#include <hip/hip_runtime.h>

#define DEVINL __device__ __forceinline__

typedef short bf16x8 __attribute__((ext_vector_type(8)));
typedef float f32x4 __attribute__((ext_vector_type(4)));

DEVINL unsigned f2b(float f) {  // f32 -> bf16 bits (round to nearest even)
  unsigned u = __float_as_uint(f);
  u = (u + 0x7FFFu + ((u >> 16) & 1u)) >> 16;
  return u & 0xFFFFu;
}
DEVINL uint4 pack8(const float* v) {
  uint4 u;
  u.x = f2b(v[0]) | (f2b(v[1]) << 16);
  u.y = f2b(v[2]) | (f2b(v[3]) << 16);
  u.z = f2b(v[4]) | (f2b(v[5]) << 16);
  u.w = f2b(v[6]) | (f2b(v[7]) << 16);
  return u;
}

// ---------------- reduction helpers ----------------
DEVINL float4 block_sum4(float4 v, float4* sh) {
  const int lane = threadIdx.x & 63, wid = threadIdx.x >> 6;
#pragma unroll
  for (int o = 32; o; o >>= 1) {
    v.x += __shfl_down(v.x, o);
    v.y += __shfl_down(v.y, o);
    v.z += __shfl_down(v.z, o);
    v.w += __shfl_down(v.w, o);
  }
  __syncthreads();
  if (lane == 0) sh[wid] = v;
  __syncthreads();
  float4 a = sh[0], b = sh[1], c = sh[2], d = sh[3], r;
  r.x = a.x + b.x + c.x + d.x;
  r.y = a.y + b.y + c.y + d.y;
  r.z = a.z + b.z + c.z + d.z;
  r.w = a.w + b.w + c.w + d.w;
  return r;
}
DEVINL float block_sum1(float v, float* sh) {
  const int lane = threadIdx.x & 63, wid = threadIdx.x >> 6;
#pragma unroll
  for (int o = 32; o; o >>= 1) v += __shfl_down(v, o);
  __syncthreads();
  if (lane == 0) sh[wid] = v;
  __syncthreads();
  return sh[0] + sh[1] + sh[2] + sh[3];
}

// ---- table projection: P[v,j] = V[v,:] @ W[:,j], P[nvec,j] = bias @ W[:,j] ----
__global__ __launch_bounds__(256) void tabproj_kernel(
    const float* __restrict__ V, const float* __restrict__ bias,
    const float* __restrict__ W, float* __restrict__ P, int nvec) {
  __shared__ float4 sh4[4];
  const int j = blockIdx.x, tid = threadIdx.x;
  float acc[4] = {0.f, 0.f, 0.f, 0.f};
  for (int kk = tid; kk < 512; kk += 256) {
    const float w = W[(size_t)kk * 512 + j];
    for (int v = 0; v < nvec; ++v) acc[v] += V[(size_t)v * 512 + kk] * w;
    acc[3] += bias[kk] * w;
  }
  float4 packed = make_float4(acc[0], acc[1], acc[2], acc[3]);
  packed = block_sum4(packed, sh4);
  if (tid == 0) {
    const float vals[4] = {packed.x, packed.y, packed.z, packed.w};
    for (int v = 0; v < nvec; ++v) P[(size_t)v * 512 + j] = vals[v];
    P[(size_t)nvec * 512 + j] = vals[3];
  }
}

// ---- weight prep: src f32 [K][N] -> dst bf16 [N][K] ----
__global__ __launch_bounds__(256) void transpose_bf_kernel(
    const float* __restrict__ src, unsigned short* __restrict__ dst, int K, int N) {
  __shared__ float tile[32][33];
  const int n0 = blockIdx.x * 32, k0 = blockIdx.y * 32;
  const int tx = threadIdx.x, ty = threadIdx.y;  // 32 x 8
#pragma unroll
  for (int r = 0; r < 4; ++r)
    tile[ty + 8 * r][tx] = src[(size_t)(k0 + ty + 8 * r) * N + n0 + tx];
  __syncthreads();
#pragma unroll
  for (int r = 0; r < 4; ++r)
    dst[(size_t)(n0 + ty + 8 * r) * K + k0 + tx] = (unsigned short)f2b(tile[tx][ty + 8 * r]);
}

// ---- pack self-side K (frag layout) + Q (packed bf16) from KVQ f32 [4096][1536] ----
// Kfr: [bh][kc=D/32][stile=64][lane=64][8]; Qbf: [bh][s][D].  nh=2, D=256.
__global__ __launch_bounds__(128) void pack_kq_kernel(
    const float* __restrict__ KVQ, unsigned short* __restrict__ Kfr,
    unsigned short* __restrict__ Qbf) {
  const int row = blockIdx.x;  // b*1024 + s
  const int b = row >> 10, s = row & 1023;
  const int t = threadIdx.x;
  const bool isQ = t >= 64;
  const int c = t & 63;
  const int h = c >> 5;           // 32 chunks of 8 per head
  const int d0 = (c & 31) * 8;
  const float* src = KVQ + (size_t)row * 1536 + (isQ ? 1024 : 0) + h * 256 + d0;
  float v[8];
  *(float4*)v = *(const float4*)src;
  *(float4*)(v + 4) = *(const float4*)(src + 4);
  const uint4 u = pack8(v);
  const int bh = b * 2 + h;
  if (isQ) {
    *(uint4*)(Qbf + ((size_t)bh * 1024 + s) * 256 + d0) = u;
  } else {
    const int kc = d0 >> 5;
    const int lane = ((d0 & 31) >> 3) * 16 + (s & 15);
    *(uint4*)(Kfr + ((size_t)(bh * 8 + kc) * 64 + (s >> 4)) * 512 + lane * 8) = u;
  }
}

// ---- V f32 [4096][ld] (head cols at h*D) -> Vfr [bh][sc=32][dtile=D/16][lane][8] ----
__global__ __launch_bounds__(256) void vtrans_frag_kernel(
    const float* __restrict__ V, int ld, int nh, int D,
    unsigned short* __restrict__ Vfr) {
  __shared__ float tile[32][33];
  const int s0 = blockIdx.x * 32, d0 = blockIdx.y * 32;
  const int bh = blockIdx.z;
  const int b = bh / nh, h = bh % nh;
  const int tx = threadIdx.x, ty = threadIdx.y;  // 32 x 8
  const float* src = V + ((size_t)b * 1024 + s0) * ld + h * D + d0;
#pragma unroll
  for (int r = 0; r < 4; ++r)
    tile[ty + 8 * r][tx] = src[(size_t)(ty + 8 * r) * ld + tx];  // [s][d]
  __syncthreads();
  const int idx = ty * 32 + tx;
  if (idx < 128) {
    const int dj = idx & 31, sch = idx >> 5;  // d within tile, s-chunk of 8
    float v[8];
#pragma unroll
    for (int jj = 0; jj < 8; ++jj) v[jj] = tile[sch * 8 + jj][dj];
    const uint4 u = pack8(v);
    const int sc = s0 >> 5;
    const int dtile = (d0 + dj) >> 4;
    const int lane = sch * 16 + (dj & 15);
    *(uint4*)(Vfr + ((size_t)(bh * 32 + sc) * (D / 16) + dtile) * 512 + lane * 8) = u;
  }
}

// ---- cross-side encoder: rank-3 affine -> Kfr + Qbf (packed) + V f32 ----
// nh=2, D=256. Tables T*: rows 0..2 = vectors, row 3 (at +1536) = bias.
__global__ __launch_bounds__(256) void affine3_pack_kernel(
    const float* __restrict__ cx, const float* __restrict__ cy, int sel,
    const float* __restrict__ TK, const float* __restrict__ TV,
    const float* __restrict__ TQ, unsigned short* __restrict__ Kfr,
    unsigned short* __restrict__ Qbf, float* __restrict__ Vf) {
  const int row = blockIdx.x;
  const int b = row >> 10, s = row & 1023;
  const float x = cx[row];
  const float* y = cy + (size_t)row * 8 + 2 * sel;
  const float y0 = y[0], y1 = y[1];
  const int t = threadIdx.x;
  if (t < 128) {
    const bool isQ = t >= 64;
    const int c = t & 63;
    const int h = c >> 5;
    const int d0 = (c & 31) * 8;
    const float* T = isQ ? TQ : TK;
    float v[8];
#pragma unroll
    for (int j = 0; j < 8; ++j) {
      const int col = h * 256 + d0 + j;
      v[j] = x * T[col] + y0 * T[512 + col] + y1 * T[1024 + col] + T[1536 + col];
    }
    const uint4 u = pack8(v);
    const int bh = b * 2 + h;
    if (isQ) {
      *(uint4*)(Qbf + ((size_t)bh * 1024 + s) * 256 + d0) = u;
    } else {
      const int kc = d0 >> 5;
      const int lane = ((d0 & 31) >> 3) * 16 + (s & 15);
      *(uint4*)(Kfr + ((size_t)(bh * 8 + kc) * 64 + (s >> 4)) * 512 + lane * 8) = u;
    }
  } else {
    const int col0 = (t - 128) * 4;
    float4 o;
    float* op = (float*)&o;
#pragma unroll
    for (int j = 0; j < 4; ++j) {
      const int col = col0 + j;
      op[j] = x * TV[col] + y0 * TV[512 + col] + y1 * TV[1024 + col] + TV[1536 + col];
    }
    *(float4*)(Vf + (size_t)row * 512 + col0) = o;
  }
}

// ---- decoder rank-1 producers (nh=4, D=128): T rows [0]=w, [1]=bias ----
__global__ __launch_bounds__(64) void rank1_pack_kernel(
    const float* __restrict__ x, const float* __restrict__ T,
    unsigned short* __restrict__ dst, int isQ) {
  const int row = blockIdx.x;
  const int b = row >> 10, s = row & 1023;
  const float xv = x[row];
  const int c = threadIdx.x;        // 64 chunks of 8
  const int h = c >> 4;             // 16 chunks per head
  const int d0 = (c & 15) * 8;
  float v[8];
#pragma unroll
  for (int j = 0; j < 8; ++j) {
    const int col = h * 128 + d0 + j;
    v[j] = xv * T[col] + T[512 + col];
  }
  const uint4 u = pack8(v);
  const int bh = b * 4 + h;
  if (isQ) {
    *(uint4*)(dst + ((size_t)bh * 1024 + s) * 128 + d0) = u;
  } else {
    const int kc = d0 >> 5;
    const int lane = ((d0 & 31) >> 3) * 16 + (s & 15);
    *(uint4*)(dst + ((size_t)(bh * 4 + kc) * 64 + (s >> 4)) * 512 + lane * 8) = u;
  }
}

// ---- f32 [4096][512] -> Qbf packed (nh=4, D=128) ----
__global__ __launch_bounds__(64) void qpack_kernel(
    const float* __restrict__ Q, unsigned short* __restrict__ Qbf) {
  const int row = blockIdx.x;
  const int b = row >> 10, s = row & 1023;
  const int c = threadIdx.x;
  const int h = c >> 4;
  const int d0 = (c & 15) * 8;
  float v[8];
  const float* src = Q + (size_t)row * 512 + h * 128 + d0;
  *(float4*)v = *(const float4*)src;
  *(float4*)(v + 4) = *(const float4*)(src + 4);
  *(uint4*)(Qbf + ((size_t)(b * 4 + h) * 1024 + s) * 128 + d0) = pack8(v);
}

// ---- out[r,:] = cx[r]*W3[0,:] + y0*W3[1,:] + y1*W3[2,:] + bias (f32 + bf16) ----
__global__ __launch_bounds__(512) void affine3_kernel(
    const float* __restrict__ cx, const float* __restrict__ cy, int sel,
    const float* __restrict__ W3, const float* __restrict__ bias,
    float* __restrict__ out, unsigned short* __restrict__ outb) {
  const int r = blockIdx.x, j = threadIdx.x;
  const float* y = cy + (size_t)r * 8 + 2 * sel;
  const float v = cx[r] * W3[j] + y[0] * W3[512 + j] + y[1] * W3[1024 + j] + bias[j];
  if (out) out[(size_t)r * 512 + j] = v;
  if (outb) outb[(size_t)r * 512 + j] = (unsigned short)f2b(v);
}

// ---- out[r,:] = x[r]*w + b ----
__global__ __launch_bounds__(512) void rank1_kernel(
    const float* __restrict__ x, const float* __restrict__ w,
    const float* __restrict__ b, float* __restrict__ out,
    unsigned short* __restrict__ outb) {
  const int r = blockIdx.x, j = threadIdx.x;
  const float v = x[r] * w[j] + b[j];
  if (out) out[(size_t)r * 512 + j] = v;
  if (outb) outb[(size_t)r * 512 + j] = (unsigned short)f2b(v);
}

// ---------------- MFMA GEMM: C = [A0 | A1] @ Wt^T (+bias), bf16 in, f32 out ------
__global__ __launch_bounds__(256) void gemm_mfma_kernel(
    const unsigned short* __restrict__ A0, int K0,
    const unsigned short* __restrict__ A1, int K1,
    const unsigned short* __restrict__ Wt, const float* __restrict__ bias,
    float* __restrict__ C, int M, int N) {
  constexpr int BM = 128, BN = 64, BK = 32, LDP = 40;
  __shared__ unsigned short As[BM * LDP];
  __shared__ unsigned short Bs[BN * LDP];
  const int tid = threadIdx.x;
  const int lane = tid & 63, w = tid >> 6;
  const int bm = blockIdx.y * BM, bn = blockIdx.x * BN;
  const int wm = (w & 1) * 64, wn = (w >> 1) * 32;
  const int l15 = lane & 15, lq = lane >> 4;
  const int ar = tid >> 1, ac = (tid & 1) * 16;
  const int br = tid >> 2, bc = (tid & 3) * 8;
  const int Ktot = K0 + K1;
  f32x4 acc[4][2] = {};
  for (int k0 = 0; k0 < Ktot; k0 += BK) {
    const unsigned short* A;
    int kk, Ak;
    if (k0 < K0) { A = A0; kk = k0;      Ak = K0; }
    else         { A = A1; kk = k0 - K0; Ak = K1; }
    const uint4 a0 = *(const uint4*)(A + (size_t)(bm + ar) * Ak + kk + ac);
    const uint4 a1 = *(const uint4*)(A + (size_t)(bm + ar) * Ak + kk + ac + 8);
    const uint4 b0 = *(const uint4*)(Wt + (size_t)(bn + br) * Ktot + k0 + bc);
    __syncthreads();
    *(uint4*)(As + ar * LDP + ac) = a0;
    *(uint4*)(As + ar * LDP + ac + 8) = a1;
    *(uint4*)(Bs + br * LDP + bc) = b0;
    __syncthreads();
    bf16x8 af[4], bfr[2];
#pragma unroll
    for (int mt = 0; mt < 4; ++mt)
      af[mt] = *(const bf16x8*)(As + (wm + mt * 16 + l15) * LDP + lq * 8);
#pragma unroll
    for (int nt = 0; nt < 2; ++nt)
      bfr[nt] = *(const bf16x8*)(Bs + (wn + nt * 16 + l15) * LDP + lq * 8);
#pragma unroll
    for (int mt = 0; mt < 4; ++mt)
#pragma unroll
      for (int nt = 0; nt < 2; ++nt)
        acc[mt][nt] =
            __builtin_amdgcn_mfma_f32_16x16x32_bf16(af[mt], bfr[nt], acc[mt][nt], 0, 0, 0);
  }
#pragma unroll
  for (int nt = 0; nt < 2; ++nt) {
    const int col = bn + wn + nt * 16 + l15;
    const float bv = bias ? bias[col] : 0.f;
#pragma unroll
    for (int mt = 0; mt < 4; ++mt) {
#pragma unroll
      for (int r = 0; r < 4; ++r) {
        const int row = bm + wm + mt * 16 + lq * 4 + r;
        C[(size_t)row * N + col] = acc[mt][nt][r] + bv;
      }
    }
  }
}

// ---------------- MFMA flash attention, frag-packed inputs ----------------
// Block = 16 q rows of one (b,head); 4 waves own 256 keys each.
// Qbf: [bh][s][D] bf16. Kfr: [bh][kc][stile][lane][8]. Vfr: [bh][sc][dtile][lane][8].
template <int D, int NKV>
__global__ __launch_bounds__(256, 2) void attn_mfma_kernel(
    const unsigned short* __restrict__ Qa, const unsigned short* __restrict__ Qb,
    const unsigned short* __restrict__ KfrA, const unsigned short* __restrict__ KfrB,
    const unsigned short* __restrict__ VfrA, const unsigned short* __restrict__ VfrB,
    float post_scale, float scale, int nh, unsigned short* __restrict__ R) {
  constexpr int NQS = NKV;
  constexpr int QP = D + 8;
  constexpr int WP = 1024 + 8;
  constexpr int DT = D / 64;
  const int tid = threadIdx.x;
  const int lane = tid & 63, w = tid >> 6;
  const int l15 = lane & 15, lq = lane >> 4;
  const int nbh = 4 * nh;
  const int bh = blockIdx.x % nbh;           // XCD-local (b,h)
  const int qb16 = (blockIdx.x / nbh) * 16;
  const int b = bh / nh, head = bh % nh;
  const size_t rowb = (size_t)b * 1024;
  const int colo = head * D;

  __shared__ unsigned short qsh[NQS * 16 * QP];
  __shared__ unsigned short wsh[16 * WP];
  __shared__ float redA[4][16];
  __shared__ float redB[4][16];

  // ---- stage Q tiles (vectorized bf16 copies) ----
  for (int idx = tid; idx < NQS * 16 * (D / 8); idx += 256) {
    const int st = idx / (16 * (D / 8));
    const int rem = idx - st * 16 * (D / 8);
    const int r = rem / (D / 8), ch = rem - r * (D / 8);
    const unsigned short* Q = st ? Qb : Qa;
    const uint4 u = *(const uint4*)(Q + ((size_t)bh * 1024 + qb16 + r) * D + ch * 8);
    *(uint4*)(qsh + st * 16 * QP + r * QP + ch * 8) = u;
  }
  __syncthreads();

  f32x4 acc_o[DT] = {};

  for (int s = 0; s < NKV; ++s) {
    const unsigned short* Kp = (s ? KfrB : KfrA) + (size_t)bh * D * 1024;
    const unsigned short* Vp = (s ? VfrB : VfrA) + (size_t)bh * D * 1024;
    // ---- QK^T: scores in C-layout regs (row=lq*4+r -> q, col=l15 -> key) ----
    f32x4 acc[NQS][16] = {};
#pragma unroll 1
    for (int kc = 0; kc < D / 32; ++kc) {
      const bf16x8 qa = *(const bf16x8*)(qsh + l15 * QP + kc * 32 + lq * 8);
      bf16x8 qb2;
      if constexpr (NKV == 2)
        qb2 = *(const bf16x8*)(qsh + 16 * QP + l15 * QP + kc * 32 + lq * 8);
#pragma unroll
      for (int st = 0; st < 16; ++st) {
        const bf16x8 kf =
            *(const bf16x8*)(Kp + ((size_t)kc * 64 + w * 16 + st) * 512 + lane * 8);
        acc[0][st] = __builtin_amdgcn_mfma_f32_16x16x32_bf16(qa, kf, acc[0][st], 0, 0, 0);
        if constexpr (NKV == 2)
          acc[1][st] = __builtin_amdgcn_mfma_f32_16x16x32_bf16(qb2, kf, acc[1][st], 0, 0, 0);
      }
    }
#pragma unroll
    for (int st = 0; st < 16; ++st) {
      acc[0][st] *= scale;
      if constexpr (NKV == 2) acc[1][st] *= scale;
    }
    // ---- row max ----
    float pmA[4], pmB[4];
#pragma unroll
    for (int r = 0; r < 4; ++r) { pmA[r] = -3e38f; pmB[r] = -3e38f; }
#pragma unroll
    for (int st = 0; st < 16; ++st)
#pragma unroll
      for (int r = 0; r < 4; ++r) {
        pmA[r] = fmaxf(pmA[r], acc[0][st][r]);
        if constexpr (NKV == 2) pmB[r] = fmaxf(pmB[r], acc[1][st][r]);
      }
#pragma unroll
    for (int o = 1; o < 16; o <<= 1)
#pragma unroll
      for (int r = 0; r < 4; ++r) {
        pmA[r] = fmaxf(pmA[r], __shfl_xor(pmA[r], o));
        if constexpr (NKV == 2) pmB[r] = fmaxf(pmB[r], __shfl_xor(pmB[r], o));
      }
    __syncthreads();
    if (l15 == 0) {
#pragma unroll
      for (int r = 0; r < 4; ++r) {
        redA[w][lq * 4 + r] = pmA[r];
        if constexpr (NKV == 2) redB[w][lq * 4 + r] = pmB[r];
      }
    }
    __syncthreads();
    float mA[4], mB[4];
#pragma unroll
    for (int r = 0; r < 4; ++r) {
      mA[r] = fmaxf(fmaxf(redA[0][lq * 4 + r], redA[1][lq * 4 + r]),
                    fmaxf(redA[2][lq * 4 + r], redA[3][lq * 4 + r]));
      if constexpr (NKV == 2)
        mB[r] = fmaxf(fmaxf(redB[0][lq * 4 + r], redB[1][lq * 4 + r]),
                      fmaxf(redB[2][lq * 4 + r], redB[3][lq * 4 + r]));
    }
    // ---- exp + row sum ----
    float psA[4] = {0.f, 0.f, 0.f, 0.f}, psB[4] = {0.f, 0.f, 0.f, 0.f};
#pragma unroll
    for (int st = 0; st < 16; ++st)
#pragma unroll
      for (int r = 0; r < 4; ++r) {
        acc[0][st][r] = __expf(acc[0][st][r] - mA[r]);
        psA[r] += acc[0][st][r];
        if constexpr (NKV == 2) {
          acc[1][st][r] = __expf(acc[1][st][r] - mB[r]);
          psB[r] += acc[1][st][r];
        }
      }
#pragma unroll
    for (int o = 1; o < 16; o <<= 1)
#pragma unroll
      for (int r = 0; r < 4; ++r) {
        psA[r] += __shfl_xor(psA[r], o);
        if constexpr (NKV == 2) psB[r] += __shfl_xor(psB[r], o);
      }
    __syncthreads();
    if (l15 == 0) {
#pragma unroll
      for (int r = 0; r < 4; ++r) {
        redA[w][lq * 4 + r] = psA[r];
        if constexpr (NKV == 2) redB[w][lq * 4 + r] = psB[r];
      }
    }
    __syncthreads();
    float invA[4], invB[4];
#pragma unroll
    for (int r = 0; r < 4; ++r) {
      invA[r] = 1.f / (redA[0][lq * 4 + r] + redA[1][lq * 4 + r] +
                       redA[2][lq * 4 + r] + redA[3][lq * 4 + r]);
      if constexpr (NKV == 2)
        invB[r] = 1.f / (redB[0][lq * 4 + r] + redB[1][lq * 4 + r] +
                         redB[2][lq * 4 + r] + redB[3][lq * 4 + r]);
    }
    // ---- combined weight strip (bf16, A-operand layout) ----
#pragma unroll
    for (int st = 0; st < 16; ++st)
#pragma unroll
      for (int r = 0; r < 4; ++r) {
        float wv = acc[0][st][r] * invA[r];
        if constexpr (NKV == 2) wv += acc[1][st][r] * invB[r];
        wsh[(lq * 4 + r) * WP + w * 256 + st * 16 + l15] = (unsigned short)f2b(wv);
      }
    __syncthreads();
    // ---- PV: out[q][d] += W[q][s] V[s][d], frag-packed V loads ----
#pragma unroll 2
    for (int sc = 0; sc < 32; ++sc) {
      const bf16x8 pa = *(const bf16x8*)(wsh + l15 * WP + sc * 32 + lq * 8);
#pragma unroll
      for (int dt = 0; dt < DT; ++dt) {
        const bf16x8 vb =
            *(const bf16x8*)(Vp + ((size_t)sc * (D / 16) + w * DT + dt) * 512 + lane * 8);
        acc_o[dt] = __builtin_amdgcn_mfma_f32_16x16x32_bf16(pa, vb, acc_o[dt], 0, 0, 0);
      }
    }
  }
  // ---- epilogue: C layout row=lq*4+r -> q, col=l15 -> d ----
#pragma unroll
  for (int dt = 0; dt < DT; ++dt)
#pragma unroll
    for (int r = 0; r < 4; ++r) {
      const int q = lq * 4 + r;
      const int d = w * (DT * 16) + dt * 16 + l15;
      R[(rowb + qb16 + q) * 512 + colo + d] = (unsigned short)f2b(acc_o[dt][r] * post_scale);
    }
}

// ------------- out = LayerNorm(G + res) * g + b  (f32 out + optional bf16 out) ----
__global__ __launch_bounds__(256) void ln_kernel(
    const float* __restrict__ G, const float* __restrict__ res,
    const float* __restrict__ g, const float* __restrict__ b,
    float* __restrict__ out, unsigned short* __restrict__ outb) {
  __shared__ float sh[4];
  const int row = blockIdx.x, tid = threadIdx.x;
  const size_t off = (size_t)row * 512;
  const float x0 = G[off + tid] + res[off + tid];
  const float x1 = G[off + tid + 256] + res[off + tid + 256];
  const float mean = block_sum1(x0 + x1, sh) * (1.0f / 512.0f);
  const float d0 = x0 - mean, d1 = x1 - mean;
  const float var = block_sum1(d0 * d0 + d1 * d1, sh) * (1.0f / 512.0f);
  const float inv = rsqrtf(var + 1e-5f);
  const float y0 = d0 * inv * g[tid] + b[tid];
  const float y1 = d1 * inv * g[tid + 256] + b[tid + 256];
  out[off + tid] = y0;
  out[off + tid + 256] = y1;
  if (outb) {
    outb[off + tid] = (unsigned short)f2b(y0);
    outb[off + tid + 256] = (unsigned short)f2b(y1);
  }
}

extern "C" void kernel_launch(void* const* d_in, const int* in_sizes, int n_in,
                              void* d_out, int out_size, void* d_ws, size_t ws_size,
                              hipStream_t stream) {
  typedef unsigned short ushort_t;
  const float* cx   = (const float*)d_in[0];
  const float* cy   = (const float*)d_in[1];
  const float* txp  = (const float*)d_in[2];
  const float* in_W = (const float*)d_in[3];
  const float* in_b = (const float*)d_in[4];
  const float* cx_W = (const float*)d_in[5];
  const float* cx_b = (const float*)d_in[6];
  const float* tx_W = (const float*)d_in[7];
  const float* tx_b = (const float*)d_in[8];
  const float* sWk  = (const float*)d_in[9];
  const float* sWv  = (const float*)d_in[10];
  const float* sWq  = (const float*)d_in[11];
  const float* sWf  = (const float*)d_in[12];
  const float* sbf  = (const float*)d_in[13];
  const float* sg   = (const float*)d_in[14];
  const float* sb   = (const float*)d_in[15];
  const float* aWk  = (const float*)d_in[16];
  const float* aWv  = (const float*)d_in[17];
  const float* aWq  = (const float*)d_in[18];
  const float* aWf  = (const float*)d_in[19];
  const float* abf  = (const float*)d_in[20];
  const float* ag   = (const float*)d_in[21];
  const float* ab   = (const float*)d_in[22];

  const size_t MB = 1024 * 1024;
  char* ws = (char*)d_ws;
  float*    E     = (float*)(ws + 0 * MB);       // 8 MB
  ushort_t* Ebf   = (ushort_t*)(ws + 8 * MB);    // 4 MB
  float*    QA    = (float*)(ws + 12 * MB);      // 8 MB
  ushort_t* QAbf  = (ushort_t*)(ws + 20 * MB);   // 4 MB
  ushort_t* Rbbf  = (ushort_t*)(ws + 24 * MB);   // 4 MB
  float*    KVQ   = (float*)(ws + 28 * MB);      // 24 MB [4096][1536] K|V|Q
  float*    G     = KVQ;                          // alias: KVQ dead before Wf GEMM
  ushort_t* KfrA  = (ushort_t*)(ws + 52 * MB);   // 4 MB
  ushort_t* VfrA  = (ushort_t*)(ws + 56 * MB);   // 4 MB
  ushort_t* QbfA  = (ushort_t*)(ws + 60 * MB);   // 4 MB
  ushort_t* KfrB  = (ushort_t*)(ws + 64 * MB);   // 4 MB
  ushort_t* VfrB  = (ushort_t*)(ws + 68 * MB);   // 4 MB
  ushort_t* QbfB  = (ushort_t*)(ws + 72 * MB);   // 4 MB
  float*    cVf   = (float*)(ws + 76 * MB);      // 8 MB cross/decoder V f32
  float*    cQf   = (float*)(ws + 84 * MB);      // 8 MB decoder Q f32
  ushort_t* Wkvqt[2] = {(ushort_t*)(ws + 92 * MB),
                        (ushort_t*)(ws + 92 * MB + 1536 * 1024)};
  ushort_t* Wft[2]   = {(ushort_t*)(ws + 95 * MB), (ushort_t*)(ws + 96 * MB)};
  ushort_t* aWvt[2]  = {(ushort_t*)(ws + 97 * MB),
                        (ushort_t*)(ws + 97 * MB + 512 * 1024)};
  ushort_t* aWqt1    = (ushort_t*)(ws + 98 * MB);
  ushort_t* aWft[2]  = {(ushort_t*)(ws + 99 * MB), (ushort_t*)(ws + 100 * MB)};
  float*    Ttab     = (float*)(ws + 101 * MB);

  float* T_sc[2][3];
  for (int i = 0; i < 2; ++i)
    for (int w = 0; w < 3; ++w) T_sc[i][w] = Ttab + (size_t)(i * 3 + w) * 2048;
  float* T_cak[2] = {Ttab + 12288, Ttab + 12288 + 1024};
  float* T_caq0 = Ttab + 14336;

  const dim3 tb(32, 8);
  const dim3 tg512(16, 16), tg1024(16, 32);

  // ---- prep: weight transposes + projection tables ----
  for (int i = 0; i < 2; ++i) {
    transpose_bf_kernel<<<tg512, tb, 0, stream>>>(sWk + (size_t)i * 262144, Wkvqt[i], 512, 512);
    transpose_bf_kernel<<<tg512, tb, 0, stream>>>(sWv + (size_t)i * 262144, Wkvqt[i] + 512 * 512, 512, 512);
    transpose_bf_kernel<<<tg512, tb, 0, stream>>>(sWq + (size_t)i * 262144, Wkvqt[i] + 1024 * 512, 512, 512);
    transpose_bf_kernel<<<tg1024, tb, 0, stream>>>(sWf + (size_t)i * 524288, Wft[i], 1024, 512);
    transpose_bf_kernel<<<tg512, tb, 0, stream>>>(aWv + (size_t)i * 262144, aWvt[i], 512, 512);
    transpose_bf_kernel<<<tg1024, tb, 0, stream>>>(aWf + (size_t)i * 524288, aWft[i], 1024, 512);
    tabproj_kernel<<<512, 256, 0, stream>>>(in_W, in_b, sWk + (size_t)i * 262144, T_sc[i][0], 3);
    tabproj_kernel<<<512, 256, 0, stream>>>(in_W, in_b, sWv + (size_t)i * 262144, T_sc[i][1], 3);
    tabproj_kernel<<<512, 256, 0, stream>>>(in_W, in_b, sWq + (size_t)i * 262144, T_sc[i][2], 3);
    tabproj_kernel<<<512, 256, 0, stream>>>(cx_W, cx_b, aWk + (size_t)i * 262144, T_cak[i], 1);
  }
  transpose_bf_kernel<<<tg512, tb, 0, stream>>>(aWq + 262144, aWqt1, 512, 512);
  tabproj_kernel<<<512, 256, 0, stream>>>(tx_W, tx_b, aWq, T_caq0, 1);

  // ---- initial activations ----
  affine3_kernel<<<4096, 512, 0, stream>>>(cx, cy, 0, in_W, in_b, E, Ebf);
  rank1_kernel<<<4096, 512, 0, stream>>>(txp, tx_W, tx_b, QA, QAbf);

  // ---- 8 self/cross encoder layers ----
  for (int p = 0; p < 4; ++p) {
    for (int i = 0; i < 2; ++i) {
      gemm_mfma_kernel<<<dim3(24, 32), 256, 0, stream>>>(Ebf, 512, nullptr, 0, Wkvqt[i],
                                                         nullptr, KVQ, 4096, 1536);
      pack_kq_kernel<<<4096, 128, 0, stream>>>(KVQ, KfrA, QbfA);
      vtrans_frag_kernel<<<dim3(32, 8, 8), tb, 0, stream>>>(KVQ + 512, 1536, 2, 256, VfrA);
      if (p > 0) {
        affine3_pack_kernel<<<4096, 256, 0, stream>>>(cx, cy, p, T_sc[i][0], T_sc[i][1],
                                                      T_sc[i][2], KfrB, QbfB, cVf);
        vtrans_frag_kernel<<<dim3(32, 8, 8), tb, 0, stream>>>(cVf, 512, 2, 256, VfrB);
        attn_mfma_kernel<256, 2><<<512, 256, 0, stream>>>(
            QbfA, QbfB, KfrA, KfrB, VfrA, VfrB, 1.0f, 0.0625f, 2, Rbbf);
      } else {
        // x2 is x: 4 identical sdpa terms -> 4 * sdpa(sQ,sK,sV)
        attn_mfma_kernel<256, 1><<<512, 256, 0, stream>>>(
            QbfA, QbfA, KfrA, KfrA, VfrA, VfrA, 4.0f, 0.0625f, 2, Rbbf);
      }
      gemm_mfma_kernel<<<dim3(8, 32), 256, 0, stream>>>(Ebf, 512, Rbbf, 512, Wft[i],
                                                        sbf + (size_t)i * 512, G, 4096, 512);
      ln_kernel<<<4096, 256, 0, stream>>>(G, E, sg + (size_t)i * 512, sb + (size_t)i * 512,
                                          E, Ebf);
    }
  }

  // ---- 2 cross-attention decoder layers (nh=4, D=128) ----
  for (int i = 0; i < 2; ++i) {
    rank1_pack_kernel<<<4096, 64, 0, stream>>>(cx, T_cak[i], KfrA, 0);
    gemm_mfma_kernel<<<dim3(8, 32), 256, 0, stream>>>(Ebf, 512, nullptr, 0, aWvt[i],
                                                      nullptr, cVf, 4096, 512);
    vtrans_frag_kernel<<<dim3(32, 4, 16), tb, 0, stream>>>(cVf, 512, 4, 128, VfrA);
    if (i == 0) {
      rank1_pack_kernel<<<4096, 64, 0, stream>>>(txp, T_caq0, QbfB, 1);
    } else {
      gemm_mfma_kernel<<<dim3(8, 32), 256, 0, stream>>>(QAbf, 512, nullptr, 0, aWqt1,
                                                        nullptr, cQf, 4096, 512);
      qpack_kernel<<<4096, 64, 0, stream>>>(cQf, QbfB);
    }
    attn_mfma_kernel<128, 1><<<1024, 256, 0, stream>>>(
        QbfB, QbfB, KfrA, KfrA, VfrA, VfrA, 1.0f, 0.08838834764831845f, 4, Rbbf);
    gemm_mfma_kernel<<<dim3(8, 32), 256, 0, stream>>>(QAbf, 512, Rbbf, 512, aWft[i],
                                                      abf + (size_t)i * 512, G, 4096, 512);
    ln_kernel<<<4096, 256, 0, stream>>>(G, QA, ag + (size_t)i * 512, ab + (size_t)i * 512,
                                        (i == 1) ? (float*)d_out : QA,
                                        (i == 1) ? nullptr : QAbf);
  }
  (void)in_sizes; (void)n_in; (void)out_size; (void)ws_size;
}

// Round 8
// 1389.353 us; speedup vs baseline: 13.6490x; 1.0688x over previous
//
#include <hip/hip_runtime.h>

#define DEVINL __device__ __forceinline__

typedef short bf16x8 __attribute__((ext_vector_type(8)));
typedef float f32x4 __attribute__((ext_vector_type(4)));

DEVINL unsigned f2b(float f) {  // f32 -> bf16 bits (round to nearest even)
  unsigned u = __float_as_uint(f);
  u = (u + 0x7FFFu + ((u >> 16) & 1u)) >> 16;
  return u & 0xFFFFu;
}
DEVINL uint4 pack8(const float* v) {
  uint4 u;
  u.x = f2b(v[0]) | (f2b(v[1]) << 16);
  u.y = f2b(v[2]) | (f2b(v[3]) << 16);
  u.z = f2b(v[4]) | (f2b(v[5]) << 16);
  u.w = f2b(v[6]) | (f2b(v[7]) << 16);
  return u;
}

// ---------------- reduction helpers ----------------
DEVINL float4 block_sum4(float4 v, float4* sh) {
  const int lane = threadIdx.x & 63, wid = threadIdx.x >> 6;
#pragma unroll
  for (int o = 32; o; o >>= 1) {
    v.x += __shfl_down(v.x, o);
    v.y += __shfl_down(v.y, o);
    v.z += __shfl_down(v.z, o);
    v.w += __shfl_down(v.w, o);
  }
  __syncthreads();
  if (lane == 0) sh[wid] = v;
  __syncthreads();
  float4 a = sh[0], b = sh[1], c = sh[2], d = sh[3], r;
  r.x = a.x + b.x + c.x + d.x;
  r.y = a.y + b.y + c.y + d.y;
  r.z = a.z + b.z + c.z + d.z;
  r.w = a.w + b.w + c.w + d.w;
  return r;
}
DEVINL float block_sum1(float v, float* sh) {
  const int lane = threadIdx.x & 63, wid = threadIdx.x >> 6;
#pragma unroll
  for (int o = 32; o; o >>= 1) v += __shfl_down(v, o);
  __syncthreads();
  if (lane == 0) sh[wid] = v;
  __syncthreads();
  return sh[0] + sh[1] + sh[2] + sh[3];
}

// ---- table projection: P[v,j] = scl*(V[v,:] @ W[:,j]), P[nvec,j] = scl*(bias @ W) ----
__global__ __launch_bounds__(256) void tabproj_kernel(
    const float* __restrict__ V, const float* __restrict__ bias,
    const float* __restrict__ W, float* __restrict__ P, int nvec, float scl) {
  __shared__ float4 sh4[4];
  const int j = blockIdx.x, tid = threadIdx.x;
  float acc[4] = {0.f, 0.f, 0.f, 0.f};
  for (int kk = tid; kk < 512; kk += 256) {
    const float w = W[(size_t)kk * 512 + j];
    for (int v = 0; v < nvec; ++v) acc[v] += V[(size_t)v * 512 + kk] * w;
    acc[3] += bias[kk] * w;
  }
  float4 packed = make_float4(acc[0], acc[1], acc[2], acc[3]);
  packed = block_sum4(packed, sh4);
  if (tid == 0) {
    const float vals[4] = {packed.x * scl, packed.y * scl, packed.z * scl, packed.w * scl};
    for (int v = 0; v < nvec; ++v) P[(size_t)v * 512 + j] = vals[v];
    P[(size_t)nvec * 512 + j] = vals[3];
  }
}

// ---- weight prep: src f32 [K][N] -> dst bf16 [N][K], scaled ----
__global__ __launch_bounds__(256) void transpose_bf_kernel(
    const float* __restrict__ src, unsigned short* __restrict__ dst, int K, int N,
    float scl) {
  __shared__ float tile[32][33];
  const int n0 = blockIdx.x * 32, k0 = blockIdx.y * 32;
  const int tx = threadIdx.x, ty = threadIdx.y;  // 32 x 8
#pragma unroll
  for (int r = 0; r < 4; ++r)
    tile[ty + 8 * r][tx] = src[(size_t)(k0 + ty + 8 * r) * N + n0 + tx];
  __syncthreads();
#pragma unroll
  for (int r = 0; r < 4; ++r)
    dst[(size_t)(n0 + ty + 8 * r) * K + k0 + tx] =
        (unsigned short)f2b(scl * tile[tx][ty + 8 * r]);
}

// ---- pack self-side K (frag layout) + Q (packed bf16) from KVQ f32 [4096][1536] ----
// Kfr: [bh][kc=D/32][stile=64][lane=64][8]; Qbf: [bh][s][D].  nh=2, D=256.
__global__ __launch_bounds__(128) void pack_kq_kernel(
    const float* __restrict__ KVQ, unsigned short* __restrict__ Kfr,
    unsigned short* __restrict__ Qbf) {
  const int row = blockIdx.x;  // b*1024 + s
  const int b = row >> 10, s = row & 1023;
  const int t = threadIdx.x;
  const bool isQ = t >= 64;
  const int c = t & 63;
  const int h = c >> 5;           // 32 chunks of 8 per head
  const int d0 = (c & 31) * 8;
  const float* src = KVQ + (size_t)row * 1536 + (isQ ? 1024 : 0) + h * 256 + d0;
  float v[8];
  *(float4*)v = *(const float4*)src;
  *(float4*)(v + 4) = *(const float4*)(src + 4);
  const uint4 u = pack8(v);
  const int bh = b * 2 + h;
  if (isQ) {
    *(uint4*)(Qbf + ((size_t)bh * 1024 + s) * 256 + d0) = u;
  } else {
    const int kc = d0 >> 5;
    const int lane = ((d0 & 31) >> 3) * 16 + (s & 15);
    *(uint4*)(Kfr + ((size_t)(bh * 8 + kc) * 64 + (s >> 4)) * 512 + lane * 8) = u;
  }
}

// ---- V f32 [4096][ld] (head cols at h*D) -> Vfr [bh][sc=32][dtile=D/16][lane][8] ----
__global__ __launch_bounds__(256) void vtrans_frag_kernel(
    const float* __restrict__ V, int ld, int nh, int D,
    unsigned short* __restrict__ Vfr) {
  __shared__ float tile[32][33];
  const int s0 = blockIdx.x * 32, d0 = blockIdx.y * 32;
  const int bh = blockIdx.z;
  const int b = bh / nh, h = bh % nh;
  const int tx = threadIdx.x, ty = threadIdx.y;  // 32 x 8
  const float* src = V + ((size_t)b * 1024 + s0) * ld + h * D + d0;
#pragma unroll
  for (int r = 0; r < 4; ++r)
    tile[ty + 8 * r][tx] = src[(size_t)(ty + 8 * r) * ld + tx];  // [s][d]
  __syncthreads();
  const int idx = ty * 32 + tx;
  if (idx < 128) {
    const int dj = idx & 31, sch = idx >> 5;  // d within tile, s-chunk of 8
    float v[8];
#pragma unroll
    for (int jj = 0; jj < 8; ++jj) v[jj] = tile[sch * 8 + jj][dj];
    const uint4 u = pack8(v);
    const int sc = s0 >> 5;
    const int dtile = (d0 + dj) >> 4;
    const int lane = sch * 16 + (dj & 15);
    *(uint4*)(Vfr + ((size_t)(bh * 32 + sc) * (D / 16) + dtile) * 512 + lane * 8) = u;
  }
}

// ---- cross-side encoder: rank-3 affine -> Kfr + Qbf (packed) + V f32 ----
// nh=2, D=256. Tables T*: rows 0..2 = vectors, row 3 (at +1536) = bias.
__global__ __launch_bounds__(256) void affine3_pack_kernel(
    const float* __restrict__ cx, const float* __restrict__ cy, int sel,
    const float* __restrict__ TK, const float* __restrict__ TV,
    const float* __restrict__ TQ, unsigned short* __restrict__ Kfr,
    unsigned short* __restrict__ Qbf, float* __restrict__ Vf) {
  const int row = blockIdx.x;
  const int b = row >> 10, s = row & 1023;
  const float x = cx[row];
  const float* y = cy + (size_t)row * 8 + 2 * sel;
  const float y0 = y[0], y1 = y[1];
  const int t = threadIdx.x;
  if (t < 128) {
    const bool isQ = t >= 64;
    const int c = t & 63;
    const int h = c >> 5;
    const int d0 = (c & 31) * 8;
    const float* T = isQ ? TQ : TK;
    float v[8];
#pragma unroll
    for (int j = 0; j < 8; ++j) {
      const int col = h * 256 + d0 + j;
      v[j] = x * T[col] + y0 * T[512 + col] + y1 * T[1024 + col] + T[1536 + col];
    }
    const uint4 u = pack8(v);
    const int bh = b * 2 + h;
    if (isQ) {
      *(uint4*)(Qbf + ((size_t)bh * 1024 + s) * 256 + d0) = u;
    } else {
      const int kc = d0 >> 5;
      const int lane = ((d0 & 31) >> 3) * 16 + (s & 15);
      *(uint4*)(Kfr + ((size_t)(bh * 8 + kc) * 64 + (s >> 4)) * 512 + lane * 8) = u;
    }
  } else {
    const int col0 = (t - 128) * 4;
    float4 o;
    float* op = (float*)&o;
#pragma unroll
    for (int j = 0; j < 4; ++j) {
      const int col = col0 + j;
      op[j] = x * TV[col] + y0 * TV[512 + col] + y1 * TV[1024 + col] + TV[1536 + col];
    }
    *(float4*)(Vf + (size_t)row * 512 + col0) = o;
  }
}

// ---- decoder rank-1 producers (nh=4, D=128): T rows [0]=w, [1]=bias ----
__global__ __launch_bounds__(64) void rank1_pack_kernel(
    const float* __restrict__ x, const float* __restrict__ T,
    unsigned short* __restrict__ dst, int isQ) {
  const int row = blockIdx.x;
  const int b = row >> 10, s = row & 1023;
  const float xv = x[row];
  const int c = threadIdx.x;        // 64 chunks of 8
  const int h = c >> 4;             // 16 chunks per head
  const int d0 = (c & 15) * 8;
  float v[8];
#pragma unroll
  for (int j = 0; j < 8; ++j) {
    const int col = h * 128 + d0 + j;
    v[j] = xv * T[col] + T[512 + col];
  }
  const uint4 u = pack8(v);
  const int bh = b * 4 + h;
  if (isQ) {
    *(uint4*)(dst + ((size_t)bh * 1024 + s) * 128 + d0) = u;
  } else {
    const int kc = d0 >> 5;
    const int lane = ((d0 & 31) >> 3) * 16 + (s & 15);
    *(uint4*)(dst + ((size_t)(bh * 4 + kc) * 64 + (s >> 4)) * 512 + lane * 8) = u;
  }
}

// ---- f32 [4096][512] -> Qbf packed (nh=4, D=128), scaled ----
__global__ __launch_bounds__(64) void qpack_kernel(
    const float* __restrict__ Q, unsigned short* __restrict__ Qbf, float scl) {
  const int row = blockIdx.x;
  const int b = row >> 10, s = row & 1023;
  const int c = threadIdx.x;
  const int h = c >> 4;
  const int d0 = (c & 15) * 8;
  float v[8];
  const float* src = Q + (size_t)row * 512 + h * 128 + d0;
  *(float4*)v = *(const float4*)src;
  *(float4*)(v + 4) = *(const float4*)(src + 4);
#pragma unroll
  for (int j = 0; j < 8; ++j) v[j] *= scl;
  *(uint4*)(Qbf + ((size_t)(b * 4 + h) * 1024 + s) * 128 + d0) = pack8(v);
}

// ---- out[r,:] = cx[r]*W3[0,:] + y0*W3[1,:] + y1*W3[2,:] + bias (f32 + bf16) ----
__global__ __launch_bounds__(512) void affine3_kernel(
    const float* __restrict__ cx, const float* __restrict__ cy, int sel,
    const float* __restrict__ W3, const float* __restrict__ bias,
    float* __restrict__ out, unsigned short* __restrict__ outb) {
  const int r = blockIdx.x, j = threadIdx.x;
  const float* y = cy + (size_t)r * 8 + 2 * sel;
  const float v = cx[r] * W3[j] + y[0] * W3[512 + j] + y[1] * W3[1024 + j] + bias[j];
  if (out) out[(size_t)r * 512 + j] = v;
  if (outb) outb[(size_t)r * 512 + j] = (unsigned short)f2b(v);
}

// ---- out[r,:] = x[r]*w + b ----
__global__ __launch_bounds__(512) void rank1_kernel(
    const float* __restrict__ x, const float* __restrict__ w,
    const float* __restrict__ b, float* __restrict__ out,
    unsigned short* __restrict__ outb) {
  const int r = blockIdx.x, j = threadIdx.x;
  const float v = x[r] * w[j] + b[j];
  if (out) out[(size_t)r * 512 + j] = v;
  if (outb) outb[(size_t)r * 512 + j] = (unsigned short)f2b(v);
}

// ---------------- MFMA GEMM: C = [A0 | A1] @ Wt^T (+bias), bf16 in, f32 out ------
__global__ __launch_bounds__(256) void gemm_mfma_kernel(
    const unsigned short* __restrict__ A0, int K0,
    const unsigned short* __restrict__ A1, int K1,
    const unsigned short* __restrict__ Wt, const float* __restrict__ bias,
    float* __restrict__ C, int M, int N) {
  constexpr int BM = 128, BN = 64, BK = 32, LDP = 40;
  __shared__ unsigned short As[BM * LDP];
  __shared__ unsigned short Bs[BN * LDP];
  const int tid = threadIdx.x;
  const int lane = tid & 63, w = tid >> 6;
  const int bm = blockIdx.y * BM, bn = blockIdx.x * BN;
  const int wm = (w & 1) * 64, wn = (w >> 1) * 32;
  const int l15 = lane & 15, lq = lane >> 4;
  const int ar = tid >> 1, ac = (tid & 1) * 16;
  const int br = tid >> 2, bc = (tid & 3) * 8;
  const int Ktot = K0 + K1;
  f32x4 acc[4][2] = {};
  for (int k0 = 0; k0 < Ktot; k0 += BK) {
    const unsigned short* A;
    int kk, Ak;
    if (k0 < K0) { A = A0; kk = k0;      Ak = K0; }
    else         { A = A1; kk = k0 - K0; Ak = K1; }
    const uint4 a0 = *(const uint4*)(A + (size_t)(bm + ar) * Ak + kk + ac);
    const uint4 a1 = *(const uint4*)(A + (size_t)(bm + ar) * Ak + kk + ac + 8);
    const uint4 b0 = *(const uint4*)(Wt + (size_t)(bn + br) * Ktot + k0 + bc);
    __syncthreads();
    *(uint4*)(As + ar * LDP + ac) = a0;
    *(uint4*)(As + ar * LDP + ac + 8) = a1;
    *(uint4*)(Bs + br * LDP + bc) = b0;
    __syncthreads();
    bf16x8 af[4], bfr[2];
#pragma unroll
    for (int mt = 0; mt < 4; ++mt)
      af[mt] = *(const bf16x8*)(As + (wm + mt * 16 + l15) * LDP + lq * 8);
#pragma unroll
    for (int nt = 0; nt < 2; ++nt)
      bfr[nt] = *(const bf16x8*)(Bs + (wn + nt * 16 + l15) * LDP + lq * 8);
#pragma unroll
    for (int mt = 0; mt < 4; ++mt)
#pragma unroll
      for (int nt = 0; nt < 2; ++nt)
        acc[mt][nt] =
            __builtin_amdgcn_mfma_f32_16x16x32_bf16(af[mt], bfr[nt], acc[mt][nt], 0, 0, 0);
  }
#pragma unroll
  for (int nt = 0; nt < 2; ++nt) {
    const int col = bn + wn + nt * 16 + l15;
    const float bv = bias ? bias[col] : 0.f;
#pragma unroll
    for (int mt = 0; mt < 4; ++mt) {
#pragma unroll
      for (int r = 0; r < 4; ++r) {
        const int row = bm + wm + mt * 16 + lq * 4 + r;
        C[(size_t)row * N + col] = acc[mt][nt][r] + bv;
      }
    }
  }
}

// ---------------- MFMA flash attention, frag-packed inputs, batched loads -------
// Block = 16 q rows of one (b,head); 4 waves own 256 keys each. Q pre-scaled.
// Qbf: [bh][s][D] bf16. Kfr: [bh][kc][stile][lane][8]. Vfr: [bh][sc][dtile][lane][8].
template <int D, int NKV>
__global__ __launch_bounds__(256, 2) void attn_mfma_kernel(
    const unsigned short* __restrict__ Qa, const unsigned short* __restrict__ Qb,
    const unsigned short* __restrict__ KfrA, const unsigned short* __restrict__ KfrB,
    const unsigned short* __restrict__ VfrA, const unsigned short* __restrict__ VfrB,
    float post_scale, int nh, unsigned short* __restrict__ R) {
  constexpr int NQS = NKV;
  constexpr int QP = D + 8;
  constexpr int WP = 1024 + 8;
  constexpr int DT = D / 64;
  const int tid = threadIdx.x;
  const int lane = tid & 63, w = tid >> 6;
  const int l15 = lane & 15, lq = lane >> 4;
  const int nbh = 4 * nh;
  const int bh = blockIdx.x % nbh;           // XCD-local (b,h)
  const int qb16 = (blockIdx.x / nbh) * 16;
  const int b = bh / nh, head = bh % nh;
  const size_t rowb = (size_t)b * 1024;
  const int colo = head * D;

  __shared__ unsigned short qsh[NQS * 16 * QP];
  __shared__ unsigned short wsh[16 * WP];
  __shared__ float redA[4][16];
  __shared__ float redB[4][16];

  // ---- stage Q tiles (vectorized bf16 copies) ----
  for (int idx = tid; idx < NQS * 16 * (D / 8); idx += 256) {
    const int st = idx / (16 * (D / 8));
    const int rem = idx - st * 16 * (D / 8);
    const int r = rem / (D / 8), ch = rem - r * (D / 8);
    const unsigned short* Q = st ? Qb : Qa;
    const uint4 u = *(const uint4*)(Q + ((size_t)bh * 1024 + qb16 + r) * D + ch * 8);
    *(uint4*)(qsh + st * 16 * QP + r * QP + ch * 8) = u;
  }
  __syncthreads();

  f32x4 acc_o[DT] = {};

  for (int s = 0; s < NKV; ++s) {
    const unsigned short* Kp = (s ? KfrB : KfrA) + (size_t)bh * D * 1024;
    const unsigned short* Vp = (s ? VfrB : VfrA) + (size_t)bh * D * 1024;
    // ---- QK^T: batched kf loads, scores in C-layout regs ----
    f32x4 acc[NQS][16] = {};
#pragma unroll 1
    for (int kc = 0; kc < D / 32; ++kc) {
      bf16x8 kf[16];
#pragma unroll
      for (int st = 0; st < 16; ++st)
        kf[st] = *(const bf16x8*)(Kp + ((size_t)kc * 64 + w * 16 + st) * 512 + lane * 8);
      const bf16x8 qa = *(const bf16x8*)(qsh + l15 * QP + kc * 32 + lq * 8);
#pragma unroll
      for (int st = 0; st < 16; ++st)
        acc[0][st] = __builtin_amdgcn_mfma_f32_16x16x32_bf16(qa, kf[st], acc[0][st], 0, 0, 0);
      if constexpr (NKV == 2) {
        const bf16x8 qb2 = *(const bf16x8*)(qsh + 16 * QP + l15 * QP + kc * 32 + lq * 8);
#pragma unroll
        for (int st = 0; st < 16; ++st)
          acc[1][st] =
              __builtin_amdgcn_mfma_f32_16x16x32_bf16(qb2, kf[st], acc[1][st], 0, 0, 0);
      }
    }
    // ---- row max ----
    float pmA[4], pmB[4];
#pragma unroll
    for (int r = 0; r < 4; ++r) { pmA[r] = -3e38f; pmB[r] = -3e38f; }
#pragma unroll
    for (int st = 0; st < 16; ++st)
#pragma unroll
      for (int r = 0; r < 4; ++r) {
        pmA[r] = fmaxf(pmA[r], acc[0][st][r]);
        if constexpr (NKV == 2) pmB[r] = fmaxf(pmB[r], acc[1][st][r]);
      }
#pragma unroll
    for (int o = 1; o < 16; o <<= 1)
#pragma unroll
      for (int r = 0; r < 4; ++r) {
        pmA[r] = fmaxf(pmA[r], __shfl_xor(pmA[r], o));
        if constexpr (NKV == 2) pmB[r] = fmaxf(pmB[r], __shfl_xor(pmB[r], o));
      }
    __syncthreads();
    if (l15 == 0) {
#pragma unroll
      for (int r = 0; r < 4; ++r) {
        redA[w][lq * 4 + r] = pmA[r];
        if constexpr (NKV == 2) redB[w][lq * 4 + r] = pmB[r];
      }
    }
    __syncthreads();
    float mA[4], mB[4];
#pragma unroll
    for (int r = 0; r < 4; ++r) {
      mA[r] = fmaxf(fmaxf(redA[0][lq * 4 + r], redA[1][lq * 4 + r]),
                    fmaxf(redA[2][lq * 4 + r], redA[3][lq * 4 + r]));
      if constexpr (NKV == 2)
        mB[r] = fmaxf(fmaxf(redB[0][lq * 4 + r], redB[1][lq * 4 + r]),
                      fmaxf(redB[2][lq * 4 + r], redB[3][lq * 4 + r]));
    }
    // ---- exp + row sum ----
    float psA[4] = {0.f, 0.f, 0.f, 0.f}, psB[4] = {0.f, 0.f, 0.f, 0.f};
#pragma unroll
    for (int st = 0; st < 16; ++st)
#pragma unroll
      for (int r = 0; r < 4; ++r) {
        acc[0][st][r] = __expf(acc[0][st][r] - mA[r]);
        psA[r] += acc[0][st][r];
        if constexpr (NKV == 2) {
          acc[1][st][r] = __expf(acc[1][st][r] - mB[r]);
          psB[r] += acc[1][st][r];
        }
      }
#pragma unroll
    for (int o = 1; o < 16; o <<= 1)
#pragma unroll
      for (int r = 0; r < 4; ++r) {
        psA[r] += __shfl_xor(psA[r], o);
        if constexpr (NKV == 2) psB[r] += __shfl_xor(psB[r], o);
      }
    __syncthreads();
    if (l15 == 0) {
#pragma unroll
      for (int r = 0; r < 4; ++r) {
        redA[w][lq * 4 + r] = psA[r];
        if constexpr (NKV == 2) redB[w][lq * 4 + r] = psB[r];
      }
    }
    __syncthreads();
    float invA[4], invB[4];
#pragma unroll
    for (int r = 0; r < 4; ++r) {
      invA[r] = 1.f / (redA[0][lq * 4 + r] + redA[1][lq * 4 + r] +
                       redA[2][lq * 4 + r] + redA[3][lq * 4 + r]);
      if constexpr (NKV == 2)
        invB[r] = 1.f / (redB[0][lq * 4 + r] + redB[1][lq * 4 + r] +
                         redB[2][lq * 4 + r] + redB[3][lq * 4 + r]);
    }
    // ---- combined weight strip (bf16, A-operand layout) ----
#pragma unroll
    for (int st = 0; st < 16; ++st)
#pragma unroll
      for (int r = 0; r < 4; ++r) {
        float wv = acc[0][st][r] * invA[r];
        if constexpr (NKV == 2) wv += acc[1][st][r] * invB[r];
        wsh[(lq * 4 + r) * WP + w * 256 + st * 16 + l15] = (unsigned short)f2b(wv);
      }
    __syncthreads();
    // ---- PV: out[q][d] += W[q][s] V[s][d]; batch 2 sc-chunks of loads ----
#pragma unroll 1
    for (int sc = 0; sc < 32; sc += 2) {
      bf16x8 pa[2], vb[2][DT];
#pragma unroll
      for (int u = 0; u < 2; ++u) {
        pa[u] = *(const bf16x8*)(wsh + l15 * WP + (sc + u) * 32 + lq * 8);
#pragma unroll
        for (int dt = 0; dt < DT; ++dt)
          vb[u][dt] = *(const bf16x8*)(
              Vp + ((size_t)(sc + u) * (D / 16) + w * DT + dt) * 512 + lane * 8);
      }
#pragma unroll
      for (int u = 0; u < 2; ++u)
#pragma unroll
        for (int dt = 0; dt < DT; ++dt)
          acc_o[dt] =
              __builtin_amdgcn_mfma_f32_16x16x32_bf16(pa[u], vb[u][dt], acc_o[dt], 0, 0, 0);
    }
  }
  // ---- epilogue: C layout row=lq*4+r -> q, col=l15 -> d ----
#pragma unroll
  for (int dt = 0; dt < DT; ++dt)
#pragma unroll
    for (int r = 0; r < 4; ++r) {
      const int q = lq * 4 + r;
      const int d = w * (DT * 16) + dt * 16 + l15;
      R[(rowb + qb16 + q) * 512 + colo + d] = (unsigned short)f2b(acc_o[dt][r] * post_scale);
    }
}

// ------------- out = LayerNorm(G + res) * g + b  (f32 out + optional bf16 out) ----
__global__ __launch_bounds__(256) void ln_kernel(
    const float* __restrict__ G, const float* __restrict__ res,
    const float* __restrict__ g, const float* __restrict__ b,
    float* __restrict__ out, unsigned short* __restrict__ outb) {
  __shared__ float sh[4];
  const int row = blockIdx.x, tid = threadIdx.x;
  const size_t off = (size_t)row * 512;
  const float x0 = G[off + tid] + res[off + tid];
  const float x1 = G[off + tid + 256] + res[off + tid + 256];
  const float mean = block_sum1(x0 + x1, sh) * (1.0f / 512.0f);
  const float d0 = x0 - mean, d1 = x1 - mean;
  const float var = block_sum1(d0 * d0 + d1 * d1, sh) * (1.0f / 512.0f);
  const float inv = rsqrtf(var + 1e-5f);
  const float y0 = d0 * inv * g[tid] + b[tid];
  const float y1 = d1 * inv * g[tid + 256] + b[tid + 256];
  out[off + tid] = y0;
  out[off + tid + 256] = y1;
  if (outb) {
    outb[off + tid] = (unsigned short)f2b(y0);
    outb[off + tid + 256] = (unsigned short)f2b(y1);
  }
}

extern "C" void kernel_launch(void* const* d_in, const int* in_sizes, int n_in,
                              void* d_out, int out_size, void* d_ws, size_t ws_size,
                              hipStream_t stream) {
  typedef unsigned short ushort_t;
  const float* cx   = (const float*)d_in[0];
  const float* cy   = (const float*)d_in[1];
  const float* txp  = (const float*)d_in[2];
  const float* in_W = (const float*)d_in[3];
  const float* in_b = (const float*)d_in[4];
  const float* cx_W = (const float*)d_in[5];
  const float* cx_b = (const float*)d_in[6];
  const float* tx_W = (const float*)d_in[7];
  const float* tx_b = (const float*)d_in[8];
  const float* sWk  = (const float*)d_in[9];
  const float* sWv  = (const float*)d_in[10];
  const float* sWq  = (const float*)d_in[11];
  const float* sWf  = (const float*)d_in[12];
  const float* sbf  = (const float*)d_in[13];
  const float* sg   = (const float*)d_in[14];
  const float* sb   = (const float*)d_in[15];
  const float* aWk  = (const float*)d_in[16];
  const float* aWv  = (const float*)d_in[17];
  const float* aWq  = (const float*)d_in[18];
  const float* aWf  = (const float*)d_in[19];
  const float* abf  = (const float*)d_in[20];
  const float* ag   = (const float*)d_in[21];
  const float* ab   = (const float*)d_in[22];

  const float SSC = 0.0625f;               // 1/sqrt(256)
  const float CSC = 0.08838834764831845f;  // 1/sqrt(128)

  const size_t MB = 1024 * 1024;
  char* ws = (char*)d_ws;
  float*    E     = (float*)(ws + 0 * MB);       // 8 MB
  ushort_t* Ebf   = (ushort_t*)(ws + 8 * MB);    // 4 MB
  float*    QA    = (float*)(ws + 12 * MB);      // 8 MB
  ushort_t* QAbf  = (ushort_t*)(ws + 20 * MB);   // 4 MB
  ushort_t* Rbbf  = (ushort_t*)(ws + 24 * MB);   // 4 MB
  float*    KVQ   = (float*)(ws + 28 * MB);      // 24 MB [4096][1536] K|V|Q
  float*    G     = KVQ;                          // alias: KVQ dead before Wf GEMM
  ushort_t* KfrA  = (ushort_t*)(ws + 52 * MB);   // 4 MB
  ushort_t* VfrA  = (ushort_t*)(ws + 56 * MB);   // 4 MB
  ushort_t* QbfA  = (ushort_t*)(ws + 60 * MB);   // 4 MB
  ushort_t* KfrB  = (ushort_t*)(ws + 64 * MB);   // 4 MB
  ushort_t* VfrB  = (ushort_t*)(ws + 68 * MB);   // 4 MB
  ushort_t* QbfB  = (ushort_t*)(ws + 72 * MB);   // 4 MB
  float*    cVf   = (float*)(ws + 76 * MB);      // 8 MB cross/decoder V f32
  float*    cQf   = (float*)(ws + 84 * MB);      // 8 MB decoder Q f32
  ushort_t* Wkvqt[2] = {(ushort_t*)(ws + 92 * MB),
                        (ushort_t*)(ws + 92 * MB + 1536 * 1024)};
  ushort_t* Wft[2]   = {(ushort_t*)(ws + 95 * MB), (ushort_t*)(ws + 96 * MB)};
  ushort_t* aWvt[2]  = {(ushort_t*)(ws + 97 * MB),
                        (ushort_t*)(ws + 97 * MB + 512 * 1024)};
  ushort_t* aWqt1    = (ushort_t*)(ws + 98 * MB);
  ushort_t* aWft[2]  = {(ushort_t*)(ws + 99 * MB), (ushort_t*)(ws + 100 * MB)};
  float*    Ttab     = (float*)(ws + 101 * MB);

  float* T_sc[2][3];
  for (int i = 0; i < 2; ++i)
    for (int w = 0; w < 3; ++w) T_sc[i][w] = Ttab + (size_t)(i * 3 + w) * 2048;
  float* T_cak[2] = {Ttab + 12288, Ttab + 12288 + 1024};
  float* T_caq0 = Ttab + 14336;

  const dim3 tb(32, 8);
  const dim3 tg512(16, 16), tg1024(16, 32);

  // ---- prep: weight transposes + projection tables (Q weights pre-scaled) ----
  for (int i = 0; i < 2; ++i) {
    transpose_bf_kernel<<<tg512, tb, 0, stream>>>(sWk + (size_t)i * 262144, Wkvqt[i], 512, 512, 1.f);
    transpose_bf_kernel<<<tg512, tb, 0, stream>>>(sWv + (size_t)i * 262144, Wkvqt[i] + 512 * 512, 512, 512, 1.f);
    transpose_bf_kernel<<<tg512, tb, 0, stream>>>(sWq + (size_t)i * 262144, Wkvqt[i] + 1024 * 512, 512, 512, SSC);
    transpose_bf_kernel<<<tg1024, tb, 0, stream>>>(sWf + (size_t)i * 524288, Wft[i], 1024, 512, 1.f);
    transpose_bf_kernel<<<tg512, tb, 0, stream>>>(aWv + (size_t)i * 262144, aWvt[i], 512, 512, 1.f);
    transpose_bf_kernel<<<tg1024, tb, 0, stream>>>(aWf + (size_t)i * 524288, aWft[i], 1024, 512, 1.f);
    tabproj_kernel<<<512, 256, 0, stream>>>(in_W, in_b, sWk + (size_t)i * 262144, T_sc[i][0], 3, 1.f);
    tabproj_kernel<<<512, 256, 0, stream>>>(in_W, in_b, sWv + (size_t)i * 262144, T_sc[i][1], 3, 1.f);
    tabproj_kernel<<<512, 256, 0, stream>>>(in_W, in_b, sWq + (size_t)i * 262144, T_sc[i][2], 3, SSC);
    tabproj_kernel<<<512, 256, 0, stream>>>(cx_W, cx_b, aWk + (size_t)i * 262144, T_cak[i], 1, 1.f);
  }
  transpose_bf_kernel<<<tg512, tb, 0, stream>>>(aWq + 262144, aWqt1, 512, 512, 1.f);
  tabproj_kernel<<<512, 256, 0, stream>>>(tx_W, tx_b, aWq, T_caq0, 1, CSC);

  // ---- initial activations ----
  affine3_kernel<<<4096, 512, 0, stream>>>(cx, cy, 0, in_W, in_b, E, Ebf);
  rank1_kernel<<<4096, 512, 0, stream>>>(txp, tx_W, tx_b, QA, QAbf);

  // ---- 8 self/cross encoder layers ----
  for (int p = 0; p < 4; ++p) {
    for (int i = 0; i < 2; ++i) {
      gemm_mfma_kernel<<<dim3(24, 32), 256, 0, stream>>>(Ebf, 512, nullptr, 0, Wkvqt[i],
                                                         nullptr, KVQ, 4096, 1536);
      pack_kq_kernel<<<4096, 128, 0, stream>>>(KVQ, KfrA, QbfA);
      vtrans_frag_kernel<<<dim3(32, 8, 8), tb, 0, stream>>>(KVQ + 512, 1536, 2, 256, VfrA);
      if (p > 0) {
        affine3_pack_kernel<<<4096, 256, 0, stream>>>(cx, cy, p, T_sc[i][0], T_sc[i][1],
                                                      T_sc[i][2], KfrB, QbfB, cVf);
        vtrans_frag_kernel<<<dim3(32, 8, 8), tb, 0, stream>>>(cVf, 512, 2, 256, VfrB);
        attn_mfma_kernel<256, 2><<<512, 256, 0, stream>>>(
            QbfA, QbfB, KfrA, KfrB, VfrA, VfrB, 1.0f, 2, Rbbf);
      } else {
        // x2 is x: 4 identical sdpa terms -> 4 * sdpa(sQ,sK,sV)
        attn_mfma_kernel<256, 1><<<512, 256, 0, stream>>>(
            QbfA, QbfA, KfrA, KfrA, VfrA, VfrA, 4.0f, 2, Rbbf);
      }
      gemm_mfma_kernel<<<dim3(8, 32), 256, 0, stream>>>(Ebf, 512, Rbbf, 512, Wft[i],
                                                        sbf + (size_t)i * 512, G, 4096, 512);
      ln_kernel<<<4096, 256, 0, stream>>>(G, E, sg + (size_t)i * 512, sb + (size_t)i * 512,
                                          E, Ebf);
    }
  }

  // ---- 2 cross-attention decoder layers (nh=4, D=128) ----
  for (int i = 0; i < 2; ++i) {
    rank1_pack_kernel<<<4096, 64, 0, stream>>>(cx, T_cak[i], KfrA, 0);
    gemm_mfma_kernel<<<dim3(8, 32), 256, 0, stream>>>(Ebf, 512, nullptr, 0, aWvt[i],
                                                      nullptr, cVf, 4096, 512);
    vtrans_frag_kernel<<<dim3(32, 4, 16), tb, 0, stream>>>(cVf, 512, 4, 128, VfrA);
    if (i == 0) {
      rank1_pack_kernel<<<4096, 64, 0, stream>>>(txp, T_caq0, QbfB, 1);
    } else {
      gemm_mfma_kernel<<<dim3(8, 32), 256, 0, stream>>>(QAbf, 512, nullptr, 0, aWqt1,
                                                        nullptr, cQf, 4096, 512);
      qpack_kernel<<<4096, 64, 0, stream>>>(cQf, QbfB, CSC);
    }
    attn_mfma_kernel<128, 1><<<1024, 256, 0, stream>>>(
        QbfB, QbfB, KfrA, KfrA, VfrA, VfrA, 1.0f, 4, Rbbf);
    gemm_mfma_kernel<<<dim3(8, 32), 256, 0, stream>>>(QAbf, 512, Rbbf, 512, aWft[i],
                                                      abf + (size_t)i * 512, G, 4096, 512);
    ln_kernel<<<4096, 256, 0, stream>>>(G, QA, ag + (size_t)i * 512, ab + (size_t)i * 512,
                                        (i == 1) ? (float*)d_out : QA,
                                        (i == 1) ? nullptr : QAbf);
  }
  (void)in_sizes; (void)n_in; (void)out_size; (void)ws_size;
}